// Round 5
// baseline (284.320 us; speedup 1.0000x reference)
//
#include <hip/hip_runtime.h>
#include <hip/hip_bf16.h>

// Problem: B=4, L=2048, E=1024, H=16, HD=64.
// NOTE: the reference's _separate_heads is reshape(B,L,E)->(B,H,L,HD) with NO
// transpose: the flat (B,L,E) buffer IS the (B,H,L,HD) buffer. Only the
// attention V-operand needs a (l',d)->(d,l') transpose (k_trv).
//
// R13/R14: staging request-granularity fix (full-line global_load_lds +
// source-side st-swizzle) -- confirmed: QKV left top-5, total 334->266.
// R15: k_attn ring-2 K/V double-buffer with counted-wait pipeline. The old
// loop was issue->syncthreads(vmcnt(0) drain)->compute: full load latency
// exposed every k-iteration. New loop: vmcnt(0) [waits buf[cur], issued one
// full compute-phase earlier -> free] -> s_barrier -> issue stage(kb+1 ->
// buf[cur^1]) -> compute(kb). One barrier/iter. setprio around MFMA clusters.
namespace {
constexpr int kB = 4, kL = 2048, kE = 1024, kH = 16, kHD = 64;
constexpr float kCs = 0.18033688f;  // log2(e)/8, folded into Q projection
}

typedef __attribute__((ext_vector_type(8))) short bf16x8;
typedef __attribute__((ext_vector_type(4))) float f32x4;

__device__ __forceinline__ short f2bf(float f) {
  __hip_bfloat16 h = __float2bfloat16(f);
  return *reinterpret_cast<short*>(&h);
}

__device__ __forceinline__ void load_lds16(const void* g, void* l) {
  __builtin_amdgcn_global_load_lds((const __attribute__((address_space(1))) void*)g,
                                   (__attribute__((address_space(3))) void*)l, 16, 0, 0);
}
__device__ __forceinline__ void load_lds4(const void* g, void* l) {
  __builtin_amdgcn_global_load_lds((const __attribute__((address_space(1))) void*)g,
                                   (__attribute__((address_space(3))) void*)l, 4, 0, 0);
}

// fp32 -> bf16 cast, 4 elems/thread
__global__ __launch_bounds__(256) void k_cvt(const float* __restrict__ s,
                                             short* __restrict__ d, int n) {
  int i = (blockIdx.x * 256 + threadIdx.x) * 4;
  if (i < n) {
    float4 v = *reinterpret_cast<const float4*>(s + i);
    short4 o;
    o.x = f2bf(v.x); o.y = f2bf(v.y); o.z = f2bf(v.z); o.w = f2bf(v.w);
    *reinterpret_cast<short4*>(d + i) = o;
  }
}

// 4 weight casts + mask->float-offset precompute, one dispatch.
__global__ __launch_bounds__(256) void k_cvtw(const float* __restrict__ w0,
                                              const float* __restrict__ w1,
                                              const float* __restrict__ w2,
                                              const float* __restrict__ w3,
                                              const int* __restrict__ mask,
                                              short* __restrict__ dst,
                                              float* __restrict__ mkf) {
  int bx = blockIdx.x;
  if (bx >= 4096) {  // mask segment: 8192 elems
    int i = (bx - 4096) * 256 + threadIdx.x;
    mkf[i] = mask[i] != 0 ? -10.0f : -1.0e10f;
    return;
  }
  int seg = bx >> 10;
  const float* s = seg == 0 ? w0 : seg == 1 ? w1 : seg == 2 ? w2 : w3;
  int local = ((bx & 1023) * 256 + threadIdx.x) * 4;
  float4 v = *reinterpret_cast<const float4*>(s + local);
  short4 o;
  o.x = f2bf(v.x); o.y = f2bf(v.y); o.z = f2bf(v.z); o.w = f2bf(v.w);
  *reinterpret_cast<short4*>(dst + seg * 1048576 + local) = o;
}

// Per-head V transpose: Vl[hb][l'][d] -> Vt[hb][d][l']. 64x64 tiles via LDS,
// both global sides coalesced.
__global__ __launch_bounds__(256) void k_trv(const short* __restrict__ Vl,
                                             short* __restrict__ Vt) {
  __shared__ unsigned T[64 * 33];
  const int t = threadIdx.x;
  const int hb = blockIdx.y;
  const int l0 = blockIdx.x * 64;
  const short* src = Vl + hb * 131072;
  short* dst = Vt + hb * 131072;
  const int d8 = (t & 7) * 8;
  const int lp = t >> 3;
  const uint4 va = *reinterpret_cast<const uint4*>(src + (l0 + 2 * lp) * 64 + d8);
  const uint4 vb = *reinterpret_cast<const uint4*>(src + (l0 + 2 * lp + 1) * 64 + d8);
  const unsigned a[4] = {va.x, va.y, va.z, va.w};
  const unsigned b[4] = {vb.x, vb.y, vb.z, vb.w};
#pragma unroll
  for (int j = 0; j < 4; ++j) {
    unsigned z0 = __builtin_amdgcn_perm(b[j], a[j], 0x05040100u);
    unsigned z1 = __builtin_amdgcn_perm(b[j], a[j], 0x07060302u);
    T[(d8 + 2 * j) * 33 + lp] = z0;
    T[(d8 + 2 * j + 1) * 33 + lp] = z1;
  }
  __syncthreads();
  const int u = (t & 7) * 4;
#pragma unroll
  for (int h2 = 0; h2 < 2; ++h2) {
    int d = (t >> 3) + h2 * 32;
    uint4 r;
    r.x = T[d * 33 + u];     r.y = T[d * 33 + u + 1];
    r.z = T[d * 33 + u + 2]; r.w = T[d * 33 + u + 3];
    *reinterpret_cast<uint4*>(dst + d * 2048 + l0 + u * 2) = r;
  }
}

// ---- deep-pipelined GEMM core: 256x128 tile, BK=64, 8 waves, ring-3 LDS ----
// (144 KiB), counted vmcnt(6) at K-tile boundaries, one barrier per K-tile.
// Staging: per instruction 8 rows x 128 B contiguous (full lines); LDS
// row-major with source-side st-swizzle (see header comment).
struct GemmCore256 {
  f32x4 acc[4][4];
  int tid, w, lane, quad, m16, wm, wn;
  __device__ __forceinline__ void run(const short* __restrict__ A,
                                      const short* __restrict__ W,
                                      int bm0, int bn0, short* S) {
    tid = threadIdx.x;
    w = tid >> 6; lane = tid & 63; quad = lane >> 4; m16 = lane & 15;
    wm = (w >> 1) * 64; wn = (w & 1) * 64;   // 4 M-waves x 2 N-waves, 64x64 each
#pragma unroll
    for (int i = 0; i < 4; ++i)
#pragma unroll
      for (int j = 0; j < 4; ++j) acc[i][j] = (f32x4){0, 0, 0, 0};

    // Staging map: per call c, row = c*64 + (tid>>3), 16-B unit =
    // (tid&7)^((tid>>3)&7) (pre-swizzled source; LDS dest linear tid*8).
    const int srow = tid >> 3;
    const int sunit = (tid & 7) ^ (srow & 7);
    const short* Ag = A + (bm0 + srow) * 1024 + sunit * 8;
    const short* Wg = W + (bn0 + srow) * 1024 + sunit * 8;
    // Frag read bases: LDS[r][s_unit] = G[r][s_unit ^ (r&7)];
    // want G[row][quad+4s] -> read unit (quad+4s)^(m16&7).
    const int x7 = m16 & 7;
    const int u0 = (quad ^ x7) * 8;   // s=0
    const int u1 = u0 ^ 32;           // s=1: ((quad+4)^x7)*8
    const int baseA = (wm + m16) * 64;
    const int baseB = 16384 + (wn + m16) * 64;

#define STG_A(Sb, T, c) load_lds16(Ag + (c) * 65536 + (T) * 64, (Sb) + (c) * 4096 + tid * 8)
#define STG_B(Sb, T, c) load_lds16(Wg + (c) * 65536 + (T) * 64, (Sb) + 16384 + (c) * 4096 + tid * 8)

    // Prologue: stage K-tiles 0 (buf0) and 1 (buf1); wait for tile 0 only.
    short* S1 = S + 24576;
    STG_A(S, 0, 0); STG_A(S, 0, 1); STG_A(S, 0, 2); STG_A(S, 0, 3);
    STG_B(S, 0, 0); STG_B(S, 0, 1);
    STG_A(S1, 1, 0); STG_A(S1, 1, 1); STG_A(S1, 1, 2); STG_A(S1, 1, 3);
    STG_B(S1, 1, 0); STG_B(S1, 1, 1);
    asm volatile("s_waitcnt vmcnt(6)" ::: "memory");
    __builtin_amdgcn_s_barrier();
    __builtin_amdgcn_sched_barrier(0);

    int bc = 0;
    for (int t = 0; t < 16; ++t) {
      short* Sc = S + bc * 24576;
      int b2 = bc + 2; if (b2 >= 3) b2 -= 3;
      short* Sp = S + b2 * 24576;
      const bool pf = (t < 14);  // tile t+2 exists

      bf16x8 a[4][2], b[4][2];
#pragma unroll
      for (int i = 0; i < 4; ++i) {
        a[i][0] = *reinterpret_cast<const bf16x8*>(&Sc[baseA + i * 1024 + u0]);
        a[i][1] = *reinterpret_cast<const bf16x8*>(&Sc[baseA + i * 1024 + u1]);
      }
#pragma unroll
      for (int j = 0; j < 4; ++j) {
        b[j][0] = *reinterpret_cast<const bf16x8*>(&Sc[baseB + j * 1024 + u0]);
        b[j][1] = *reinterpret_cast<const bf16x8*>(&Sc[baseB + j * 1024 + u1]);
      }
      if (pf) {
        STG_A(Sp, t + 2, 0); STG_A(Sp, t + 2, 1); STG_A(Sp, t + 2, 2); STG_A(Sp, t + 2, 3);
        STG_B(Sp, t + 2, 0); STG_B(Sp, t + 2, 1);
      }
      __builtin_amdgcn_s_setprio(1);
#pragma unroll
      for (int i = 0; i < 4; ++i)
#pragma unroll
        for (int j = 0; j < 4; ++j) {
          acc[i][j] = __builtin_amdgcn_mfma_f32_16x16x32_bf16(a[i][0], b[j][0], acc[i][j], 0, 0, 0);
          acc[i][j] = __builtin_amdgcn_mfma_f32_16x16x32_bf16(a[i][1], b[j][1], acc[i][j], 0, 0, 0);
        }
      __builtin_amdgcn_s_setprio(0);
      // K-tile boundary: everything except tile t+2's 6 chunks must be in LDS.
      if (pf) { asm volatile("s_waitcnt vmcnt(6)" ::: "memory"); }
      else    { asm volatile("s_waitcnt vmcnt(0)" ::: "memory"); }
      __builtin_amdgcn_s_barrier();
      __builtin_amdgcn_sched_barrier(0);
      bc += 1; if (bc >= 3) bc -= 3;
    }
#undef STG_A
#undef STG_B
  }
};

// Fused Q/K/V projection, XCD-swizzled: 768 blocks = 3 exact full rounds of
// 256 CUs at 1 block/CU (144 KiB LDS). 4 row-panels/XCD -> 2 MB A working
// set per XCD (L2-resident); all 24 col-blocks of a panel on the same XCD.
__global__ __launch_bounds__(512, 2) void k_gemm_qkv(const short* __restrict__ xb,
                                                     const short* __restrict__ Wq,
                                                     const short* __restrict__ Wk,
                                                     const short* __restrict__ Wv,
                                                     const float* __restrict__ bq,
                                                     const float* __restrict__ bk,
                                                     const float* __restrict__ bv,
                                                     short* __restrict__ Q,
                                                     short* __restrict__ K,
                                                     short* __restrict__ Vl) {
  __shared__ __attribute__((aligned(16))) short S[73728];  // 144 KiB, ring-3
  const int l = blockIdx.x + 24 * blockIdx.y;  // 0..767
  const int xcd = l & 7, wv_ = l >> 3;         // wv_: 0..95
  const int bm0 = (xcd + 8 * (wv_ & 3)) * 256;
  const int colsel = wv_ >> 2;                 // 0..23
  const int sel = colsel >> 3;
  const int bn0 = (colsel & 7) * 128;
  const short* W = sel == 0 ? Wq : sel == 1 ? Wk : Wv;
  const float* bias = sel == 0 ? bq : sel == 1 ? bk : bv;

  GemmCore256 g;
  g.run(xb, W, bm0, bn0, S);

  float bj[4];
#pragma unroll
  for (int j = 0; j < 4; ++j) bj[j] = bias[bn0 + g.wn + j * 16 + g.m16];

  short* C = sel == 0 ? Q : sel == 1 ? K : Vl;
  float sc = sel == 0 ? kCs : 1.0f;
#pragma unroll
  for (int i = 0; i < 4; ++i)
#pragma unroll
    for (int j = 0; j < 4; ++j)
#pragma unroll
      for (int rg = 0; rg < 4; ++rg) {
        int row = bm0 + g.wm + i * 16 + g.quad * 4 + rg;
        int col = bn0 + g.wn + j * 16 + g.m16;
        C[row * 1024 + col] = f2bf((g.acc[i][j][rg] + bj[j]) * sc);
      }
}

// Output projection: fp32 row-major out. 256 blocks = 1 exact full round.
__global__ __launch_bounds__(512, 2) void k_gemm_out(const short* __restrict__ A,
                                                     const short* __restrict__ Wo,
                                                     const float* __restrict__ bo,
                                                     float* __restrict__ C) {
  __shared__ __attribute__((aligned(16))) short S[73728];
  const int l = blockIdx.x + 8 * blockIdx.y;  // 0..255
  const int xcd = l & 7, wv_ = l >> 3;        // wv_: 0..31
  const int bm0 = (xcd + 8 * (wv_ & 3)) * 256;
  const int bn0 = (wv_ >> 2) * 128;
  GemmCore256 g;
  g.run(A, Wo, bm0, bn0, S);
  float bj[4];
#pragma unroll
  for (int j = 0; j < 4; ++j) bj[j] = bo[bn0 + g.wn + j * 16 + g.m16];
#pragma unroll
  for (int i = 0; i < 4; ++i)
#pragma unroll
    for (int j = 0; j < 4; ++j)
#pragma unroll
      for (int rg = 0; rg < 4; ++rg) {
        int row = bm0 + g.wm + i * 16 + g.quad * 4 + rg;
        int col = bn0 + g.wn + j * 16 + g.m16;
        C[row * 1024 + col] = g.acc[i][j][rg] + bj[j];
      }
}

// Flash-style attention, S^T formulation. R15: ring-2 double-buffered K/V/M
// staging with counted-wait pipeline (one raw barrier per iter; stage(kb+1)
// issued right after the barrier, drained by next iter's vmcnt(0) which is
// hidden behind a full compute phase). setprio(1) around MFMA clusters.
__global__ __launch_bounds__(256, 3) void k_attn(const short* __restrict__ Q,
                                                 const short* __restrict__ Km,
                                                 const short* __restrict__ Vt,
                                                 const float* __restrict__ Mg,
                                                 short* __restrict__ Out) {
  __shared__ __attribute__((aligned(16))) short U[8448];   // Qs then Ps (alias)
  __shared__ __attribute__((aligned(16))) short Ks[8192];  // 2 x 64x64, swizzled
  __shared__ __attribute__((aligned(16))) short Vs[8192];  // 2 x (64 d-rows x 64 keys)
  __shared__ __attribute__((aligned(16))) float Mk[128];   // 2 x 64

  const int tid = threadIdx.x;
  const int w = tid >> 6, lane = tid & 63;
  const int quad = lane >> 4, m16 = lane & 15;
  const int lid = blockIdx.x + 16 * blockIdx.y;  // 0..1023
  const int xcd = lid & 7, wv_ = lid >> 3;       // wv_: 0..127
  const int hb = xcd + 8 * (wv_ & 7);
  const int qb = wv_ >> 3;                       // 0..15
  const int b = hb >> 4, h = hb & 15;
  const int wb = w * 2112;

  const short* Qh = Q + hb * (kL * kHD) + qb * 128 * kHD;
  const short* Kh = Km + hb * (kL * kHD);
  const short* Vh = Vt + hb * (kL * kHD);
  const float* Mb = Mg + b * kL;

  // Staging map (256 threads): row = c*32 + (tid>>3), unit = (tid&7)^((tid>>3)&7).
  const int srow = tid >> 3;
  const int sunit = (tid & 7) ^ (srow & 7);
  const int x7 = m16 & 7;
  const int u0 = (quad ^ x7) * 8;
  const int u1 = u0 ^ 32;

#define STAGE_KV(kb_, buf_)                                                        \
  do {                                                                             \
    int kbase_ = (kb_) * 64;                                                       \
    load_lds16(Kh + (kbase_ + srow) * 64 + sunit * 8, &Ks[(buf_) * 4096 + tid * 8]); \
    load_lds16(Kh + (kbase_ + 32 + srow) * 64 + sunit * 8,                         \
               &Ks[(buf_) * 4096 + 2048 + tid * 8]);                               \
    load_lds16(Vh + srow * 2048 + kbase_ + sunit * 8, &Vs[(buf_) * 4096 + tid * 8]); \
    load_lds16(Vh + (32 + srow) * 2048 + kbase_ + sunit * 8,                       \
               &Vs[(buf_) * 4096 + 2048 + tid * 8]);                               \
    load_lds4(Mb + kbase_ + lane, &Mk[(buf_) * 64 + lane]);                        \
  } while (0)

#pragma unroll
  for (int c = 0; c < 4; ++c)
    load_lds16(Qh + (c * 32 + srow) * 64 + sunit * 8, &U[c * 2048 + tid * 8]);
  __syncthreads();
  bf16x8 qf[2][2];
#pragma unroll
  for (int i = 0; i < 2; ++i) {
    qf[i][0] = *reinterpret_cast<const bf16x8*>(&U[(w * 32 + i * 16 + m16) * 64 + u0]);
    qf[i][1] = *reinterpret_cast<const bf16x8*>(&U[(w * 32 + i * 16 + m16) * 64 + u1]);
  }

  bf16x8 ones;
#pragma unroll
  for (int e = 0; e < 8; ++e) ones[e] = (short)0x3F80;  // bf16 1.0

  f32x4 oacc[2][4] = {};
  f32x4 lacc[2] = {};

  // Prologue: stage kb=0; ensure own qf ds_reads landed before first barrier
  // (U alias: other waves' P-writes follow that barrier).
  STAGE_KV(0, 0);
  asm volatile("s_waitcnt lgkmcnt(0)" ::: "memory");

  for (int kb = 0; kb < 32; ++kb) {
    const int cur = kb & 1;
    const int kvb = cur * 4096;
    // buf[cur]'s 5 loads are the only outstanding VMEM (issued one full
    // compute phase ago -> this wait is ~free).
    asm volatile("s_waitcnt vmcnt(0)" ::: "memory");
    __builtin_amdgcn_s_barrier();   // all waves: buf[cur] staged, buf[cur^1] free
    __builtin_amdgcn_sched_barrier(0);
    if (kb < 31) STAGE_KV(kb + 1, cur ^ 1);

    // S^T tiles: ST[j][i], j = key-tile (rows), i = q-tile (cols).
    f32x4 ST[4][2];
    __builtin_amdgcn_s_setprio(1);
#pragma unroll
    for (int j = 0; j < 4; ++j) {
      float4 mj4 = *reinterpret_cast<const float4*>(&Mk[cur * 64 + j * 16 + quad * 4]);
      f32x4 init; init[0] = mj4.x; init[1] = mj4.y; init[2] = mj4.z; init[3] = mj4.w;
#pragma unroll
      for (int i = 0; i < 2; ++i) ST[j][i] = init;
      bf16x8 kf0 = *reinterpret_cast<const bf16x8*>(&Ks[kvb + (j * 16 + m16) * 64 + u0]);
      bf16x8 kf1 = *reinterpret_cast<const bf16x8*>(&Ks[kvb + (j * 16 + m16) * 64 + u1]);
#pragma unroll
      for (int i = 0; i < 2; ++i) {
        ST[j][i] = __builtin_amdgcn_mfma_f32_16x16x32_bf16(kf0, qf[i][0], ST[j][i], 0, 0, 0);
        ST[j][i] = __builtin_amdgcn_mfma_f32_16x16x32_bf16(kf1, qf[i][1], ST[j][i], 0, 0, 0);
      }
    }
    __builtin_amdgcn_s_setprio(0);

    // Softmax numerator + truncation pack + b64 spill into P (A-layout).
    const int kc_w = (quad >> 1);
    const int inner = (quad & 1) * 4;
#pragma unroll
    for (int j = 0; j < 4; ++j)
#pragma unroll
      for (int i = 0; i < 2; ++i) {
        float p0 = __builtin_amdgcn_exp2f(ST[j][i][0]);
        float p1 = __builtin_amdgcn_exp2f(ST[j][i][1]);
        float p2 = __builtin_amdgcn_exp2f(ST[j][i][2]);
        float p3 = __builtin_amdgcn_exp2f(ST[j][i][3]);
        uint2 pk;
        pk.x = __builtin_amdgcn_perm(__builtin_bit_cast(unsigned, p1),
                                     __builtin_bit_cast(unsigned, p0), 0x07060302u);
        pk.y = __builtin_amdgcn_perm(__builtin_bit_cast(unsigned, p3),
                                     __builtin_bit_cast(unsigned, p2), 0x07060302u);
        *reinterpret_cast<uint2*>(
            &U[wb + (j * 2 + kc_w) * 264 + (i * 16 + m16) * 8 + inner]) = pk;
      }
    asm volatile("s_waitcnt lgkmcnt(0)" ::: "memory");  // own-wave P RAW

    bf16x8 pf[2][2];
#pragma unroll
    for (int i = 0; i < 2; ++i)
#pragma unroll
      for (int s = 0; s < 2; ++s)
        pf[i][s] = *reinterpret_cast<const bf16x8*>(
            &U[wb + (s * 4 + quad) * 264 + (i * 16 + m16) * 8]);

    // l-accumulate via ones-MFMA: lacc rows == oacc rows (C-layout).
    __builtin_amdgcn_s_setprio(1);
#pragma unroll
    for (int i = 0; i < 2; ++i) {
      lacc[i] = __builtin_amdgcn_mfma_f32_16x16x32_bf16(pf[i][0], ones, lacc[i], 0, 0, 0);
      lacc[i] = __builtin_amdgcn_mfma_f32_16x16x32_bf16(pf[i][1], ones, lacc[i], 0, 0, 0);
    }

#pragma unroll
    for (int j = 0; j < 4; ++j) {
      bf16x8 vf0 = *reinterpret_cast<const bf16x8*>(&Vs[kvb + (j * 16 + m16) * 64 + u0]);
      bf16x8 vf1 = *reinterpret_cast<const bf16x8*>(&Vs[kvb + (j * 16 + m16) * 64 + u1]);
#pragma unroll
      for (int i = 0; i < 2; ++i) {
        oacc[i][j] = __builtin_amdgcn_mfma_f32_16x16x32_bf16(pf[i][0], vf0, oacc[i][j], 0, 0, 0);
        oacc[i][j] = __builtin_amdgcn_mfma_f32_16x16x32_bf16(pf[i][1], vf1, oacc[i][j], 0, 0, 0);
      }
    }
    __builtin_amdgcn_s_setprio(0);
  }
#undef STAGE_KV

#pragma unroll
  for (int i = 0; i < 2; ++i)
#pragma unroll
    for (int j = 0; j < 4; ++j) {
      int d = j * 16 + m16;
#pragma unroll
      for (int rg = 0; rg < 4; ++rg) {
        int ql = qb * 128 + w * 32 + i * 16 + quad * 4 + rg;
        Out[(b * kL + ql) * kE + h * kHD + d] =
            f2bf(oacc[i][j][rg] / lacc[i][rg]);
      }
    }
}

extern "C" void kernel_launch(void* const* d_in, const int* in_sizes, int n_in,
                              void* d_out, int out_size, void* d_ws, size_t ws_size,
                              hipStream_t stream) {
  const float* x  = (const float*)d_in[0];
  const int* mask = (const int*)d_in[1];
  const float* Wq = (const float*)d_in[2];
  const float* bq = (const float*)d_in[3];
  const float* Wk = (const float*)d_in[4];
  const float* bk = (const float*)d_in[5];
  const float* Wv = (const float*)d_in[6];
  const float* bv = (const float*)d_in[7];
  const float* Wo = (const float*)d_in[8];
  const float* bo = (const float*)d_in[9];

  short* ws  = (short*)d_ws;
  short* xb  = ws;                  // 8388608 shorts
  short* Wqb = xb  + 8388608;       // 4 x 1048576, contiguous
  short* Wkb = Wqb + 1048576;
  short* Wvb = Wkb + 1048576;
  short* Wob = Wvb + 1048576;
  short* Qb  = Wob + 1048576;       // 8388608 each
  short* Kb  = Qb  + 8388608;
  short* Vtb = Kb  + 8388608;
  short* AOb = Vtb + 8388608;       // doubles as Vl before attention runs
  float* Mkf = (float*)(AOb + 8388608);  // 8192 floats

  k_cvt<<<8192, 256, 0, stream>>>(x, xb, 8388608);
  k_cvtw<<<4128, 256, 0, stream>>>(Wq, Wk, Wv, Wo, mask, Wqb, Mkf);

  // V row-major into AOb (dead until attention runs), then transpose into Vtb.
  k_gemm_qkv<<<dim3(24, 32), 512, 0, stream>>>(xb, Wqb, Wkb, Wvb, bq, bk, bv, Qb, Kb, AOb);
  k_trv<<<dim3(32, 64), 256, 0, stream>>>(AOb, Vtb);
  k_attn<<<dim3(16, 64), 256, 0, stream>>>(Qb, Kb, Vtb, Mkf, AOb);
  k_gemm_out<<<dim3(8, 32), 512, 0, stream>>>(AOb, Wob, bo, (float*)d_out);
}

// Round 7
// 265.320 us; speedup vs baseline: 1.0716x; 1.0716x over previous
//
#include <hip/hip_runtime.h>
#include <hip/hip_bf16.h>

// Problem: B=4, L=2048, E=1024, H=16, HD=64.
// NOTE: the reference's _separate_heads is reshape(B,L,E)->(B,H,L,HD) with NO
// transpose: the flat (B,L,E) buffer IS the (B,H,L,HD) buffer. Only the
// attention V-operand needs a (l',d)->(d,l') transpose (k_trv).
//
// R13/R14: staging request-granularity fix (full-line global_load_lds +
// source-side st-swizzle) -- confirmed: total 334->266.
// R15: attn ring-2 dbuf REGRESSED (92.9->120us; TLP already hid latency,
// dbuf cost LDS/locality). Reverted.
// R16 (resubmit R17 after infra failure): attn widened to 8 waves /
// 256 q-rows / block (512 blocks, 2/CU, all co-resident): staging instrs
// 5->3 per iter, barriers & K/V traffic per q-row halved, waves/SIMD 3->4.
// setprio around MFMA clusters only.
namespace {
constexpr int kB = 4, kL = 2048, kE = 1024, kH = 16, kHD = 64;
constexpr float kCs = 0.18033688f;  // log2(e)/8, folded into Q projection
}

typedef __attribute__((ext_vector_type(8))) short bf16x8;
typedef __attribute__((ext_vector_type(4))) float f32x4;

__device__ __forceinline__ short f2bf(float f) {
  __hip_bfloat16 h = __float2bfloat16(f);
  return *reinterpret_cast<short*>(&h);
}

__device__ __forceinline__ void load_lds16(const void* g, void* l) {
  __builtin_amdgcn_global_load_lds((const __attribute__((address_space(1))) void*)g,
                                   (__attribute__((address_space(3))) void*)l, 16, 0, 0);
}
__device__ __forceinline__ void load_lds4(const void* g, void* l) {
  __builtin_amdgcn_global_load_lds((const __attribute__((address_space(1))) void*)g,
                                   (__attribute__((address_space(3))) void*)l, 4, 0, 0);
}

// fp32 -> bf16 cast, 4 elems/thread
__global__ __launch_bounds__(256) void k_cvt(const float* __restrict__ s,
                                             short* __restrict__ d, int n) {
  int i = (blockIdx.x * 256 + threadIdx.x) * 4;
  if (i < n) {
    float4 v = *reinterpret_cast<const float4*>(s + i);
    short4 o;
    o.x = f2bf(v.x); o.y = f2bf(v.y); o.z = f2bf(v.z); o.w = f2bf(v.w);
    *reinterpret_cast<short4*>(d + i) = o;
  }
}

// 4 weight casts + mask->float-offset precompute, one dispatch.
__global__ __launch_bounds__(256) void k_cvtw(const float* __restrict__ w0,
                                              const float* __restrict__ w1,
                                              const float* __restrict__ w2,
                                              const float* __restrict__ w3,
                                              const int* __restrict__ mask,
                                              short* __restrict__ dst,
                                              float* __restrict__ mkf) {
  int bx = blockIdx.x;
  if (bx >= 4096) {  // mask segment: 8192 elems
    int i = (bx - 4096) * 256 + threadIdx.x;
    mkf[i] = mask[i] != 0 ? -10.0f : -1.0e10f;
    return;
  }
  int seg = bx >> 10;
  const float* s = seg == 0 ? w0 : seg == 1 ? w1 : seg == 2 ? w2 : w3;
  int local = ((bx & 1023) * 256 + threadIdx.x) * 4;
  float4 v = *reinterpret_cast<const float4*>(s + local);
  short4 o;
  o.x = f2bf(v.x); o.y = f2bf(v.y); o.z = f2bf(v.z); o.w = f2bf(v.w);
  *reinterpret_cast<short4*>(dst + seg * 1048576 + local) = o;
}

// Per-head V transpose: Vl[hb][l'][d] -> Vt[hb][d][l']. 64x64 tiles via LDS,
// both global sides coalesced.
__global__ __launch_bounds__(256) void k_trv(const short* __restrict__ Vl,
                                             short* __restrict__ Vt) {
  __shared__ unsigned T[64 * 33];
  const int t = threadIdx.x;
  const int hb = blockIdx.y;
  const int l0 = blockIdx.x * 64;
  const short* src = Vl + hb * 131072;
  short* dst = Vt + hb * 131072;
  const int d8 = (t & 7) * 8;
  const int lp = t >> 3;
  const uint4 va = *reinterpret_cast<const uint4*>(src + (l0 + 2 * lp) * 64 + d8);
  const uint4 vb = *reinterpret_cast<const uint4*>(src + (l0 + 2 * lp + 1) * 64 + d8);
  const unsigned a[4] = {va.x, va.y, va.z, va.w};
  const unsigned b[4] = {vb.x, vb.y, vb.z, vb.w};
#pragma unroll
  for (int j = 0; j < 4; ++j) {
    unsigned z0 = __builtin_amdgcn_perm(b[j], a[j], 0x05040100u);
    unsigned z1 = __builtin_amdgcn_perm(b[j], a[j], 0x07060302u);
    T[(d8 + 2 * j) * 33 + lp] = z0;
    T[(d8 + 2 * j + 1) * 33 + lp] = z1;
  }
  __syncthreads();
  const int u = (t & 7) * 4;
#pragma unroll
  for (int h2 = 0; h2 < 2; ++h2) {
    int d = (t >> 3) + h2 * 32;
    uint4 r;
    r.x = T[d * 33 + u];     r.y = T[d * 33 + u + 1];
    r.z = T[d * 33 + u + 2]; r.w = T[d * 33 + u + 3];
    *reinterpret_cast<uint4*>(dst + d * 2048 + l0 + u * 2) = r;
  }
}

// ---- deep-pipelined GEMM core: 256x128 tile, BK=64, 8 waves, ring-3 LDS ----
// (144 KiB), counted vmcnt(6) at K-tile boundaries, one barrier per K-tile.
// Staging: per instruction 8 rows x 128 B contiguous (full lines); LDS
// row-major with source-side st-swizzle (see header comment).
struct GemmCore256 {
  f32x4 acc[4][4];
  int tid, w, lane, quad, m16, wm, wn;
  __device__ __forceinline__ void run(const short* __restrict__ A,
                                      const short* __restrict__ W,
                                      int bm0, int bn0, short* S) {
    tid = threadIdx.x;
    w = tid >> 6; lane = tid & 63; quad = lane >> 4; m16 = lane & 15;
    wm = (w >> 1) * 64; wn = (w & 1) * 64;   // 4 M-waves x 2 N-waves, 64x64 each
#pragma unroll
    for (int i = 0; i < 4; ++i)
#pragma unroll
      for (int j = 0; j < 4; ++j) acc[i][j] = (f32x4){0, 0, 0, 0};

    // Staging map: per call c, row = c*64 + (tid>>3), 16-B unit =
    // (tid&7)^((tid>>3)&7) (pre-swizzled source; LDS dest linear tid*8).
    const int srow = tid >> 3;
    const int sunit = (tid & 7) ^ (srow & 7);
    const short* Ag = A + (bm0 + srow) * 1024 + sunit * 8;
    const short* Wg = W + (bn0 + srow) * 1024 + sunit * 8;
    // Frag read bases: LDS[r][s_unit] = G[r][s_unit ^ (r&7)];
    // want G[row][quad+4s] -> read unit (quad+4s)^(m16&7).
    const int x7 = m16 & 7;
    const int u0 = (quad ^ x7) * 8;   // s=0
    const int u1 = u0 ^ 32;           // s=1: ((quad+4)^x7)*8
    const int baseA = (wm + m16) * 64;
    const int baseB = 16384 + (wn + m16) * 64;

#define STG_A(Sb, T, c) load_lds16(Ag + (c) * 65536 + (T) * 64, (Sb) + (c) * 4096 + tid * 8)
#define STG_B(Sb, T, c) load_lds16(Wg + (c) * 65536 + (T) * 64, (Sb) + 16384 + (c) * 4096 + tid * 8)

    // Prologue: stage K-tiles 0 (buf0) and 1 (buf1); wait for tile 0 only.
    short* S1 = S + 24576;
    STG_A(S, 0, 0); STG_A(S, 0, 1); STG_A(S, 0, 2); STG_A(S, 0, 3);
    STG_B(S, 0, 0); STG_B(S, 0, 1);
    STG_A(S1, 1, 0); STG_A(S1, 1, 1); STG_A(S1, 1, 2); STG_A(S1, 1, 3);
    STG_B(S1, 1, 0); STG_B(S1, 1, 1);
    asm volatile("s_waitcnt vmcnt(6)" ::: "memory");
    __builtin_amdgcn_s_barrier();
    __builtin_amdgcn_sched_barrier(0);

    int bc = 0;
    for (int t = 0; t < 16; ++t) {
      short* Sc = S + bc * 24576;
      int b2 = bc + 2; if (b2 >= 3) b2 -= 3;
      short* Sp = S + b2 * 24576;
      const bool pf = (t < 14);  // tile t+2 exists

      bf16x8 a[4][2], b[4][2];
#pragma unroll
      for (int i = 0; i < 4; ++i) {
        a[i][0] = *reinterpret_cast<const bf16x8*>(&Sc[baseA + i * 1024 + u0]);
        a[i][1] = *reinterpret_cast<const bf16x8*>(&Sc[baseA + i * 1024 + u1]);
      }
#pragma unroll
      for (int j = 0; j < 4; ++j) {
        b[j][0] = *reinterpret_cast<const bf16x8*>(&Sc[baseB + j * 1024 + u0]);
        b[j][1] = *reinterpret_cast<const bf16x8*>(&Sc[baseB + j * 1024 + u1]);
      }
      if (pf) {
        STG_A(Sp, t + 2, 0); STG_A(Sp, t + 2, 1); STG_A(Sp, t + 2, 2); STG_A(Sp, t + 2, 3);
        STG_B(Sp, t + 2, 0); STG_B(Sp, t + 2, 1);
      }
      __builtin_amdgcn_s_setprio(1);
#pragma unroll
      for (int i = 0; i < 4; ++i)
#pragma unroll
        for (int j = 0; j < 4; ++j) {
          acc[i][j] = __builtin_amdgcn_mfma_f32_16x16x32_bf16(a[i][0], b[j][0], acc[i][j], 0, 0, 0);
          acc[i][j] = __builtin_amdgcn_mfma_f32_16x16x32_bf16(a[i][1], b[j][1], acc[i][j], 0, 0, 0);
        }
      __builtin_amdgcn_s_setprio(0);
      // K-tile boundary: everything except tile t+2's 6 chunks must be in LDS.
      if (pf) { asm volatile("s_waitcnt vmcnt(6)" ::: "memory"); }
      else    { asm volatile("s_waitcnt vmcnt(0)" ::: "memory"); }
      __builtin_amdgcn_s_barrier();
      __builtin_amdgcn_sched_barrier(0);
      bc += 1; if (bc >= 3) bc -= 3;
    }
#undef STG_A
#undef STG_B
  }
};

// Fused Q/K/V projection, XCD-swizzled: 768 blocks = 3 exact full rounds of
// 256 CUs at 1 block/CU (144 KiB LDS). 4 row-panels/XCD -> 2 MB A working
// set per XCD (L2-resident); all 24 col-blocks of a panel on the same XCD.
__global__ __launch_bounds__(512, 2) void k_gemm_qkv(const short* __restrict__ xb,
                                                     const short* __restrict__ Wq,
                                                     const short* __restrict__ Wk,
                                                     const short* __restrict__ Wv,
                                                     const float* __restrict__ bq,
                                                     const float* __restrict__ bk,
                                                     const float* __restrict__ bv,
                                                     short* __restrict__ Q,
                                                     short* __restrict__ K,
                                                     short* __restrict__ Vl) {
  __shared__ __attribute__((aligned(16))) short S[73728];  // 144 KiB, ring-3
  const int l = blockIdx.x + 24 * blockIdx.y;  // 0..767
  const int xcd = l & 7, wv_ = l >> 3;         // wv_: 0..95
  const int bm0 = (xcd + 8 * (wv_ & 3)) * 256;
  const int colsel = wv_ >> 2;                 // 0..23
  const int sel = colsel >> 3;
  const int bn0 = (colsel & 7) * 128;
  const short* W = sel == 0 ? Wq : sel == 1 ? Wk : Wv;
  const float* bias = sel == 0 ? bq : sel == 1 ? bk : bv;

  GemmCore256 g;
  g.run(xb, W, bm0, bn0, S);

  float bj[4];
#pragma unroll
  for (int j = 0; j < 4; ++j) bj[j] = bias[bn0 + g.wn + j * 16 + g.m16];

  short* C = sel == 0 ? Q : sel == 1 ? K : Vl;
  float sc = sel == 0 ? kCs : 1.0f;
#pragma unroll
  for (int i = 0; i < 4; ++i)
#pragma unroll
    for (int j = 0; j < 4; ++j)
#pragma unroll
      for (int rg = 0; rg < 4; ++rg) {
        int row = bm0 + g.wm + i * 16 + g.quad * 4 + rg;
        int col = bn0 + g.wn + j * 16 + g.m16;
        C[row * 1024 + col] = f2bf((g.acc[i][j][rg] + bj[j]) * sc);
      }
}

// Output projection: fp32 row-major out. 256 blocks = 1 exact full round.
__global__ __launch_bounds__(512, 2) void k_gemm_out(const short* __restrict__ A,
                                                     const short* __restrict__ Wo,
                                                     const float* __restrict__ bo,
                                                     float* __restrict__ C) {
  __shared__ __attribute__((aligned(16))) short S[73728];
  const int l = blockIdx.x + 8 * blockIdx.y;  // 0..255
  const int xcd = l & 7, wv_ = l >> 3;        // wv_: 0..31
  const int bm0 = (xcd + 8 * (wv_ & 3)) * 256;
  const int bn0 = (wv_ >> 2) * 128;
  GemmCore256 g;
  g.run(A, Wo, bm0, bn0, S);
  float bj[4];
#pragma unroll
  for (int j = 0; j < 4; ++j) bj[j] = bo[bn0 + g.wn + j * 16 + g.m16];
#pragma unroll
  for (int i = 0; i < 4; ++i)
#pragma unroll
    for (int j = 0; j < 4; ++j)
#pragma unroll
      for (int rg = 0; rg < 4; ++rg) {
        int row = bm0 + g.wm + i * 16 + g.quad * 4 + rg;
        int col = bn0 + g.wn + j * 16 + g.m16;
        C[row * 1024 + col] = g.acc[i][j][rg] + bj[j];
      }
}

// Flash-style attention, S^T formulation. 8 waves / 256 q-rows / block.
// Proven R14 sync structure (stage -> sync -> compute -> sync, single
// buffer, TLP hides latency). Full-line staging w/ source-side st-swizzle:
// one 8-KB global_load_lds covers a whole 64x64 K (or V^T) tile.
__global__ __launch_bounds__(512, 4) void k_attn(const short* __restrict__ Q,
                                                 const short* __restrict__ Km,
                                                 const short* __restrict__ Vt,
                                                 const float* __restrict__ Mg,
                                                 short* __restrict__ Out) {
  __shared__ __attribute__((aligned(16))) short U[16896];  // Qs(16384) / Ps(8x2112) alias
  __shared__ __attribute__((aligned(16))) short Ks[4096];  // 64x64, swizzled
  __shared__ __attribute__((aligned(16))) short Vs[4096];  // 64 d-rows x 64 keys
  __shared__ __attribute__((aligned(16))) float Mk[64];

  const int tid = threadIdx.x;
  const int w = tid >> 6, lane = tid & 63;
  const int quad = lane >> 4, m16 = lane & 15;
  const int lid = blockIdx.x + 8 * blockIdx.y;   // 0..511
  const int xcd = lid & 7, wv_ = lid >> 3;       // wv_: 0..63
  const int hb = xcd + 8 * (wv_ & 7);
  const int qb = wv_ >> 3;                       // 0..7
  const int b = hb >> 4, h = hb & 15;
  const int wb = w * 2112;

  const short* Qh = Q + hb * (kL * kHD) + qb * 256 * kHD;
  const short* Kh = Km + hb * (kL * kHD);
  const short* Vh = Vt + hb * (kL * kHD);
  const float* Mb = Mg + b * kL;

  // Staging map (512 threads): row = tid>>3 (0..63), unit = (tid&7)^(row&7).
  // One instruction = 64 rows x 128 B = full 64x64 bf16 tile.
  const int srow = tid >> 3;
  const int sunit = (tid & 7) ^ (srow & 7);
  const int x7 = m16 & 7;
  const int u0 = (quad ^ x7) * 8;
  const int u1 = u0 ^ 32;

#pragma unroll
  for (int c = 0; c < 4; ++c)
    load_lds16(Qh + (c * 64 + srow) * 64 + sunit * 8, &U[c * 4096 + tid * 8]);
  __syncthreads();
  bf16x8 qf[2][2];
#pragma unroll
  for (int i = 0; i < 2; ++i) {
    qf[i][0] = *reinterpret_cast<const bf16x8*>(&U[(w * 32 + i * 16 + m16) * 64 + u0]);
    qf[i][1] = *reinterpret_cast<const bf16x8*>(&U[(w * 32 + i * 16 + m16) * 64 + u1]);
  }

  bf16x8 ones;
#pragma unroll
  for (int e = 0; e < 8; ++e) ones[e] = (short)0x3F80;  // bf16 1.0

  f32x4 oacc[2][4] = {};
  f32x4 lacc[2] = {};

  for (int kb = 0; kb < 32; ++kb) {
    int kbase = kb * 64;
    load_lds16(Kh + (kbase + srow) * 64 + sunit * 8, &Ks[tid * 8]);
    load_lds16(Vh + srow * 2048 + kbase + sunit * 8, &Vs[tid * 8]);
    load_lds4(Mb + kbase + lane, &Mk[lane]);
    __syncthreads();  // also orders all waves' qf reads before iter-0 Ps writes

    // S^T tiles: ST[j][i], j = key-tile (rows), i = q-tile (cols).
    f32x4 ST[4][2];
    __builtin_amdgcn_s_setprio(1);
#pragma unroll
    for (int j = 0; j < 4; ++j) {
      float4 mj4 = *reinterpret_cast<const float4*>(&Mk[j * 16 + quad * 4]);
      f32x4 init; init[0] = mj4.x; init[1] = mj4.y; init[2] = mj4.z; init[3] = mj4.w;
#pragma unroll
      for (int i = 0; i < 2; ++i) ST[j][i] = init;
      bf16x8 kf0 = *reinterpret_cast<const bf16x8*>(&Ks[(j * 16 + m16) * 64 + u0]);
      bf16x8 kf1 = *reinterpret_cast<const bf16x8*>(&Ks[(j * 16 + m16) * 64 + u1]);
#pragma unroll
      for (int i = 0; i < 2; ++i) {
        ST[j][i] = __builtin_amdgcn_mfma_f32_16x16x32_bf16(kf0, qf[i][0], ST[j][i], 0, 0, 0);
        ST[j][i] = __builtin_amdgcn_mfma_f32_16x16x32_bf16(kf1, qf[i][1], ST[j][i], 0, 0, 0);
      }
    }
    __builtin_amdgcn_s_setprio(0);

    // Softmax numerator + truncation pack + b64 spill into P (A-layout).
    const int kc_w = (quad >> 1);
    const int inner = (quad & 1) * 4;
#pragma unroll
    for (int j = 0; j < 4; ++j)
#pragma unroll
      for (int i = 0; i < 2; ++i) {
        float p0 = __builtin_amdgcn_exp2f(ST[j][i][0]);
        float p1 = __builtin_amdgcn_exp2f(ST[j][i][1]);
        float p2 = __builtin_amdgcn_exp2f(ST[j][i][2]);
        float p3 = __builtin_amdgcn_exp2f(ST[j][i][3]);
        uint2 pk;
        pk.x = __builtin_amdgcn_perm(__builtin_bit_cast(unsigned, p1),
                                     __builtin_bit_cast(unsigned, p0), 0x07060302u);
        pk.y = __builtin_amdgcn_perm(__builtin_bit_cast(unsigned, p3),
                                     __builtin_bit_cast(unsigned, p2), 0x07060302u);
        *reinterpret_cast<uint2*>(
            &U[wb + (j * 2 + kc_w) * 264 + (i * 16 + m16) * 8 + inner]) = pk;
      }
    asm volatile("s_waitcnt lgkmcnt(0)" ::: "memory");  // own-wave P RAW

    bf16x8 pf[2][2];
#pragma unroll
    for (int i = 0; i < 2; ++i)
#pragma unroll
      for (int s = 0; s < 2; ++s)
        pf[i][s] = *reinterpret_cast<const bf16x8*>(
            &U[wb + (s * 4 + quad) * 264 + (i * 16 + m16) * 8]);

    // l-accumulate via ones-MFMA: lacc rows == oacc rows (C-layout).
    __builtin_amdgcn_s_setprio(1);
#pragma unroll
    for (int i = 0; i < 2; ++i) {
      lacc[i] = __builtin_amdgcn_mfma_f32_16x16x32_bf16(pf[i][0], ones, lacc[i], 0, 0, 0);
      lacc[i] = __builtin_amdgcn_mfma_f32_16x16x32_bf16(pf[i][1], ones, lacc[i], 0, 0, 0);
    }

#pragma unroll
    for (int j = 0; j < 4; ++j) {
      bf16x8 vf0 = *reinterpret_cast<const bf16x8*>(&Vs[(j * 16 + m16) * 64 + u0]);
      bf16x8 vf1 = *reinterpret_cast<const bf16x8*>(&Vs[(j * 16 + m16) * 64 + u1]);
#pragma unroll
      for (int i = 0; i < 2; ++i) {
        oacc[i][j] = __builtin_amdgcn_mfma_f32_16x16x32_bf16(pf[i][0], vf0, oacc[i][j], 0, 0, 0);
        oacc[i][j] = __builtin_amdgcn_mfma_f32_16x16x32_bf16(pf[i][1], vf1, oacc[i][j], 0, 0, 0);
      }
    }
    __builtin_amdgcn_s_setprio(0);
    __syncthreads();
  }

#pragma unroll
  for (int i = 0; i < 2; ++i)
#pragma unroll
    for (int j = 0; j < 4; ++j) {
      int d = j * 16 + m16;
#pragma unroll
      for (int rg = 0; rg < 4; ++rg) {
        int ql = qb * 256 + w * 32 + i * 16 + quad * 4 + rg;
        Out[(b * kL + ql) * kE + h * kHD + d] =
            f2bf(oacc[i][j][rg] / lacc[i][rg]);
      }
    }
}

extern "C" void kernel_launch(void* const* d_in, const int* in_sizes, int n_in,
                              void* d_out, int out_size, void* d_ws, size_t ws_size,
                              hipStream_t stream) {
  const float* x  = (const float*)d_in[0];
  const int* mask = (const int*)d_in[1];
  const float* Wq = (const float*)d_in[2];
  const float* bq = (const float*)d_in[3];
  const float* Wk = (const float*)d_in[4];
  const float* bk = (const float*)d_in[5];
  const float* Wv = (const float*)d_in[6];
  const float* bv = (const float*)d_in[7];
  const float* Wo = (const float*)d_in[8];
  const float* bo = (const float*)d_in[9];

  short* ws  = (short*)d_ws;
  short* xb  = ws;                  // 8388608 shorts
  short* Wqb = xb  + 8388608;       // 4 x 1048576, contiguous
  short* Wkb = Wqb + 1048576;
  short* Wvb = Wkb + 1048576;
  short* Wob = Wvb + 1048576;
  short* Qb  = Wob + 1048576;       // 8388608 each
  short* Kb  = Qb  + 8388608;
  short* Vtb = Kb  + 8388608;
  short* AOb = Vtb + 8388608;       // doubles as Vl before attention runs
  float* Mkf = (float*)(AOb + 8388608);  // 8192 floats

  k_cvt<<<8192, 256, 0, stream>>>(x, xb, 8388608);
  k_cvtw<<<4128, 256, 0, stream>>>(Wq, Wk, Wv, Wo, mask, Wqb, Mkf);

  // V row-major into AOb (dead until attention runs), then transpose into Vtb.
  k_gemm_qkv<<<dim3(24, 32), 512, 0, stream>>>(xb, Wqb, Wkb, Wvb, bq, bk, bv, Qb, Kb, AOb);
  k_trv<<<dim3(32, 64), 256, 0, stream>>>(AOb, Vtb);
  k_attn<<<dim3(8, 64), 512, 0, stream>>>(Qb, Kb, Vtb, Mkf, AOb);
  k_gemm_out<<<dim3(8, 32), 512, 0, stream>>>(AOb, Wob, bo, (float*)d_out);
}

// Round 9
// 262.050 us; speedup vs baseline: 1.0850x; 1.0125x over previous
//
#include <hip/hip_runtime.h>
#include <hip/hip_bf16.h>

// Problem: B=4, L=2048, E=1024, H=16, HD=64.
// NOTE: the reference's _separate_heads is reshape(B,L,E)->(B,H,L,HD) with NO
// transpose: the flat (B,L,E) buffer IS the (B,H,L,HD) buffer. Within a batch
// flat idx lr*1024+e maps to h=lr>>7, l=(lr&127)*16+(e>>6), hd=e&63 -- the
// head comes from ROW bits. Hence: V transpose must stay a separate
// POSITIONAL pass (k_trv treats each 131072-elem chunk as [2048][64]);
// a fused GEMM-epilogue V^T is wrong-mapping / non-coalescable (R8, and
// prior session R7/R8).
//
// R13/R14: staging request-granularity fix (full-line global_load_lds +
// source-side st-swizzle): total 334->266.
// R16/R17: attn 8 waves / 256 q-rows / block: attn 92.9->74.4us (43% MfmaUtil).
// R18: V^T-fusion FAILED correctness (documented trap). Reverted.
// R19: keep only the safe half of R18: k_prep fuses x-cast + weight-casts +
// mask precompute into one dispatch. 5 launches: prep->qkv->trv->attn->out.
namespace {
constexpr int kB = 4, kL = 2048, kE = 1024, kH = 16, kHD = 64;
constexpr float kCs = 0.18033688f;  // log2(e)/8, folded into Q projection
}

typedef __attribute__((ext_vector_type(8))) short bf16x8;
typedef __attribute__((ext_vector_type(4))) float f32x4;

__device__ __forceinline__ short f2bf(float f) {
  __hip_bfloat16 h = __float2bfloat16(f);
  return *reinterpret_cast<short*>(&h);
}

__device__ __forceinline__ void load_lds16(const void* g, void* l) {
  __builtin_amdgcn_global_load_lds((const __attribute__((address_space(1))) void*)g,
                                   (__attribute__((address_space(3))) void*)l, 16, 0, 0);
}
__device__ __forceinline__ void load_lds4(const void* g, void* l) {
  __builtin_amdgcn_global_load_lds((const __attribute__((address_space(1))) void*)g,
                                   (__attribute__((address_space(3))) void*)l, 4, 0, 0);
}

// Fused prep: x cast (blocks 0..8191), 4 weight casts (8192..12287),
// mask->float offsets (12288..12319). One dispatch.
__global__ __launch_bounds__(256) void k_prep(const float* __restrict__ x,
                                              const float* __restrict__ w0,
                                              const float* __restrict__ w1,
                                              const float* __restrict__ w2,
                                              const float* __restrict__ w3,
                                              const int* __restrict__ mask,
                                              short* __restrict__ xb,
                                              short* __restrict__ wdst,
                                              float* __restrict__ mkf) {
  const int bx = blockIdx.x;
  const int tid = threadIdx.x;
  if (bx < 8192) {
    int i = (bx * 256 + tid) * 4;
    float4 v = *reinterpret_cast<const float4*>(x + i);
    short4 o;
    o.x = f2bf(v.x); o.y = f2bf(v.y); o.z = f2bf(v.z); o.w = f2bf(v.w);
    *reinterpret_cast<short4*>(xb + i) = o;
  } else if (bx < 12288) {
    int b2 = bx - 8192;
    int seg = b2 >> 10;
    const float* s = seg == 0 ? w0 : seg == 1 ? w1 : seg == 2 ? w2 : w3;
    int local = ((b2 & 1023) * 256 + tid) * 4;
    float4 v = *reinterpret_cast<const float4*>(s + local);
    short4 o;
    o.x = f2bf(v.x); o.y = f2bf(v.y); o.z = f2bf(v.z); o.w = f2bf(v.w);
    *reinterpret_cast<short4*>(wdst + seg * 1048576 + local) = o;
  } else {
    int i = (bx - 12288) * 256 + tid;
    mkf[i] = mask[i] != 0 ? -10.0f : -1.0e10f;
  }
}

// Per-head V transpose: Vl[hb][l'][d] -> Vt[hb][d][l']. 64x64 tiles via LDS,
// both global sides coalesced. POSITIONAL on the flat buffer (see header).
__global__ __launch_bounds__(256) void k_trv(const short* __restrict__ Vl,
                                             short* __restrict__ Vt) {
  __shared__ unsigned T[64 * 33];
  const int t = threadIdx.x;
  const int hb = blockIdx.y;
  const int l0 = blockIdx.x * 64;
  const short* src = Vl + hb * 131072;
  short* dst = Vt + hb * 131072;
  const int d8 = (t & 7) * 8;
  const int lp = t >> 3;
  const uint4 va = *reinterpret_cast<const uint4*>(src + (l0 + 2 * lp) * 64 + d8);
  const uint4 vb = *reinterpret_cast<const uint4*>(src + (l0 + 2 * lp + 1) * 64 + d8);
  const unsigned a[4] = {va.x, va.y, va.z, va.w};
  const unsigned b[4] = {vb.x, vb.y, vb.z, vb.w};
#pragma unroll
  for (int j = 0; j < 4; ++j) {
    unsigned z0 = __builtin_amdgcn_perm(b[j], a[j], 0x05040100u);
    unsigned z1 = __builtin_amdgcn_perm(b[j], a[j], 0x07060302u);
    T[(d8 + 2 * j) * 33 + lp] = z0;
    T[(d8 + 2 * j + 1) * 33 + lp] = z1;
  }
  __syncthreads();
  const int u = (t & 7) * 4;
#pragma unroll
  for (int h2 = 0; h2 < 2; ++h2) {
    int d = (t >> 3) + h2 * 32;
    uint4 r;
    r.x = T[d * 33 + u];     r.y = T[d * 33 + u + 1];
    r.z = T[d * 33 + u + 2]; r.w = T[d * 33 + u + 3];
    *reinterpret_cast<uint4*>(dst + d * 2048 + l0 + u * 2) = r;
  }
}

// ---- deep-pipelined GEMM core: 256x128 tile, BK=64, 8 waves, ring-3 LDS ----
// (144 KiB), counted vmcnt(6) at K-tile boundaries, one barrier per K-tile.
// Staging: per instruction 8 rows x 128 B contiguous (full lines); LDS
// row-major [row][64] with source-side st-swizzle: LDS[r][s] = G[r][s^(r&7)];
// frag ds_read_b128 reads unit (quad+4s)^(m16&7) -> 2-way max (free).
struct GemmCore256 {
  f32x4 acc[4][4];
  int tid, w, lane, quad, m16, wm, wn;
  __device__ __forceinline__ void run(const short* __restrict__ A,
                                      const short* __restrict__ W,
                                      int bm0, int bn0, short* S) {
    tid = threadIdx.x;
    w = tid >> 6; lane = tid & 63; quad = lane >> 4; m16 = lane & 15;
    wm = (w >> 1) * 64; wn = (w & 1) * 64;   // 4 M-waves x 2 N-waves, 64x64 each
#pragma unroll
    for (int i = 0; i < 4; ++i)
#pragma unroll
      for (int j = 0; j < 4; ++j) acc[i][j] = (f32x4){0, 0, 0, 0};

    const int srow = tid >> 3;
    const int sunit = (tid & 7) ^ (srow & 7);
    const short* Ag = A + (bm0 + srow) * 1024 + sunit * 8;
    const short* Wg = W + (bn0 + srow) * 1024 + sunit * 8;
    const int x7 = m16 & 7;
    const int u0 = (quad ^ x7) * 8;   // s=0
    const int u1 = u0 ^ 32;           // s=1
    const int baseA = (wm + m16) * 64;
    const int baseB = 16384 + (wn + m16) * 64;

#define STG_A(Sb, T, c) load_lds16(Ag + (c) * 65536 + (T) * 64, (Sb) + (c) * 4096 + tid * 8)
#define STG_B(Sb, T, c) load_lds16(Wg + (c) * 65536 + (T) * 64, (Sb) + 16384 + (c) * 4096 + tid * 8)

    // Prologue: stage K-tiles 0 (buf0) and 1 (buf1); wait for tile 0 only.
    short* S1 = S + 24576;
    STG_A(S, 0, 0); STG_A(S, 0, 1); STG_A(S, 0, 2); STG_A(S, 0, 3);
    STG_B(S, 0, 0); STG_B(S, 0, 1);
    STG_A(S1, 1, 0); STG_A(S1, 1, 1); STG_A(S1, 1, 2); STG_A(S1, 1, 3);
    STG_B(S1, 1, 0); STG_B(S1, 1, 1);
    asm volatile("s_waitcnt vmcnt(6)" ::: "memory");
    __builtin_amdgcn_s_barrier();
    __builtin_amdgcn_sched_barrier(0);

    int bc = 0;
    for (int t = 0; t < 16; ++t) {
      short* Sc = S + bc * 24576;
      int b2 = bc + 2; if (b2 >= 3) b2 -= 3;
      short* Sp = S + b2 * 24576;
      const bool pf = (t < 14);  // tile t+2 exists

      bf16x8 a[4][2], b[4][2];
#pragma unroll
      for (int i = 0; i < 4; ++i) {
        a[i][0] = *reinterpret_cast<const bf16x8*>(&Sc[baseA + i * 1024 + u0]);
        a[i][1] = *reinterpret_cast<const bf16x8*>(&Sc[baseA + i * 1024 + u1]);
      }
#pragma unroll
      for (int j = 0; j < 4; ++j) {
        b[j][0] = *reinterpret_cast<const bf16x8*>(&Sc[baseB + j * 1024 + u0]);
        b[j][1] = *reinterpret_cast<const bf16x8*>(&Sc[baseB + j * 1024 + u1]);
      }
      if (pf) {
        STG_A(Sp, t + 2, 0); STG_A(Sp, t + 2, 1); STG_A(Sp, t + 2, 2); STG_A(Sp, t + 2, 3);
        STG_B(Sp, t + 2, 0); STG_B(Sp, t + 2, 1);
      }
      __builtin_amdgcn_s_setprio(1);
#pragma unroll
      for (int i = 0; i < 4; ++i)
#pragma unroll
        for (int j = 0; j < 4; ++j) {
          acc[i][j] = __builtin_amdgcn_mfma_f32_16x16x32_bf16(a[i][0], b[j][0], acc[i][j], 0, 0, 0);
          acc[i][j] = __builtin_amdgcn_mfma_f32_16x16x32_bf16(a[i][1], b[j][1], acc[i][j], 0, 0, 0);
        }
      __builtin_amdgcn_s_setprio(0);
      if (pf) { asm volatile("s_waitcnt vmcnt(6)" ::: "memory"); }
      else    { asm volatile("s_waitcnt vmcnt(0)" ::: "memory"); }
      __builtin_amdgcn_s_barrier();
      __builtin_amdgcn_sched_barrier(0);
      bc += 1; if (bc >= 3) bc -= 3;
    }
#undef STG_A
#undef STG_B
  }
};

// Fused Q/K/V projection, XCD-swizzled: 768 blocks = 3 exact full rounds of
// 256 CUs at 1 block/CU (144 KiB LDS). 4 row-panels/XCD -> 2 MB A working
// set per XCD (L2-resident); all 24 col-blocks of a panel on the same XCD.
__global__ __launch_bounds__(512, 2) void k_gemm_qkv(const short* __restrict__ xb,
                                                     const short* __restrict__ Wq,
                                                     const short* __restrict__ Wk,
                                                     const short* __restrict__ Wv,
                                                     const float* __restrict__ bq,
                                                     const float* __restrict__ bk,
                                                     const float* __restrict__ bv,
                                                     short* __restrict__ Q,
                                                     short* __restrict__ K,
                                                     short* __restrict__ Vl) {
  __shared__ __attribute__((aligned(16))) short S[73728];  // 144 KiB, ring-3
  const int l = blockIdx.x + 24 * blockIdx.y;  // 0..767
  const int xcd = l & 7, wv_ = l >> 3;         // wv_: 0..95
  const int bm0 = (xcd + 8 * (wv_ & 3)) * 256;
  const int colsel = wv_ >> 2;                 // 0..23
  const int sel = colsel >> 3;
  const int bn0 = (colsel & 7) * 128;
  const short* W = sel == 0 ? Wq : sel == 1 ? Wk : Wv;
  const float* bias = sel == 0 ? bq : sel == 1 ? bk : bv;

  GemmCore256 g;
  g.run(xb, W, bm0, bn0, S);

  float bj[4];
#pragma unroll
  for (int j = 0; j < 4; ++j) bj[j] = bias[bn0 + g.wn + j * 16 + g.m16];

  short* C = sel == 0 ? Q : sel == 1 ? K : Vl;
  float sc = sel == 0 ? kCs : 1.0f;
#pragma unroll
  for (int i = 0; i < 4; ++i)
#pragma unroll
    for (int j = 0; j < 4; ++j)
#pragma unroll
      for (int rg = 0; rg < 4; ++rg) {
        int row = bm0 + g.wm + i * 16 + g.quad * 4 + rg;
        int col = bn0 + g.wn + j * 16 + g.m16;
        C[row * 1024 + col] = f2bf((g.acc[i][j][rg] + bj[j]) * sc);
      }
}

// Output projection: fp32 row-major out. 256 blocks = 1 exact full round.
__global__ __launch_bounds__(512, 2) void k_gemm_out(const short* __restrict__ A,
                                                     const short* __restrict__ Wo,
                                                     const float* __restrict__ bo,
                                                     float* __restrict__ C) {
  __shared__ __attribute__((aligned(16))) short S[73728];
  const int l = blockIdx.x + 8 * blockIdx.y;  // 0..255
  const int xcd = l & 7, wv_ = l >> 3;        // wv_: 0..31
  const int bm0 = (xcd + 8 * (wv_ & 3)) * 256;
  const int bn0 = (wv_ >> 2) * 128;
  GemmCore256 g;
  g.run(A, Wo, bm0, bn0, S);
  float bj[4];
#pragma unroll
  for (int j = 0; j < 4; ++j) bj[j] = bo[bn0 + g.wn + j * 16 + g.m16];
#pragma unroll
  for (int i = 0; i < 4; ++i)
#pragma unroll
    for (int j = 0; j < 4; ++j)
#pragma unroll
      for (int rg = 0; rg < 4; ++rg) {
        int row = bm0 + g.wm + i * 16 + g.quad * 4 + rg;
        int col = bn0 + g.wn + j * 16 + g.m16;
        C[row * 1024 + col] = g.acc[i][j][rg] + bj[j];
      }
}

// Flash-style attention, S^T formulation. 8 waves / 256 q-rows / block.
// Stage -> sync -> compute -> sync, single buffer (TLP hides latency).
// Full-line staging w/ source-side st-swizzle; one 8-KB global_load_lds
// covers a whole 64x64 K (or V^T) tile.
__global__ __launch_bounds__(512, 4) void k_attn(const short* __restrict__ Q,
                                                 const short* __restrict__ Km,
                                                 const short* __restrict__ Vt,
                                                 const float* __restrict__ Mg,
                                                 short* __restrict__ Out) {
  __shared__ __attribute__((aligned(16))) short U[16896];  // Qs(16384) / Ps(8x2112) alias
  __shared__ __attribute__((aligned(16))) short Ks[4096];  // 64x64, swizzled
  __shared__ __attribute__((aligned(16))) short Vs[4096];  // 64 d-rows x 64 keys
  __shared__ __attribute__((aligned(16))) float Mk[64];

  const int tid = threadIdx.x;
  const int w = tid >> 6, lane = tid & 63;
  const int quad = lane >> 4, m16 = lane & 15;
  const int lid = blockIdx.x + 8 * blockIdx.y;   // 0..511
  const int xcd = lid & 7, wv_ = lid >> 3;       // wv_: 0..63
  const int hb = xcd + 8 * (wv_ & 7);
  const int qb = wv_ >> 3;                       // 0..7
  const int b = hb >> 4, h = hb & 15;
  const int wb = w * 2112;

  const short* Qh = Q + hb * (kL * kHD) + qb * 256 * kHD;
  const short* Kh = Km + hb * (kL * kHD);
  const short* Vh = Vt + hb * (kL * kHD);
  const float* Mb = Mg + b * kL;

  const int srow = tid >> 3;
  const int sunit = (tid & 7) ^ (srow & 7);
  const int x7 = m16 & 7;
  const int u0 = (quad ^ x7) * 8;
  const int u1 = u0 ^ 32;

#pragma unroll
  for (int c = 0; c < 4; ++c)
    load_lds16(Qh + (c * 64 + srow) * 64 + sunit * 8, &U[c * 4096 + tid * 8]);
  __syncthreads();
  bf16x8 qf[2][2];
#pragma unroll
  for (int i = 0; i < 2; ++i) {
    qf[i][0] = *reinterpret_cast<const bf16x8*>(&U[(w * 32 + i * 16 + m16) * 64 + u0]);
    qf[i][1] = *reinterpret_cast<const bf16x8*>(&U[(w * 32 + i * 16 + m16) * 64 + u1]);
  }

  bf16x8 ones;
#pragma unroll
  for (int e = 0; e < 8; ++e) ones[e] = (short)0x3F80;  // bf16 1.0

  f32x4 oacc[2][4] = {};
  f32x4 lacc[2] = {};

  for (int kb = 0; kb < 32; ++kb) {
    int kbase = kb * 64;
    load_lds16(Kh + (kbase + srow) * 64 + sunit * 8, &Ks[tid * 8]);
    load_lds16(Vh + srow * 2048 + kbase + sunit * 8, &Vs[tid * 8]);
    load_lds4(Mb + kbase + lane, &Mk[lane]);
    __syncthreads();  // also orders all waves' qf reads before iter-0 Ps writes

    // S^T tiles: ST[j][i], j = key-tile (rows), i = q-tile (cols).
    f32x4 ST[4][2];
    __builtin_amdgcn_s_setprio(1);
#pragma unroll
    for (int j = 0; j < 4; ++j) {
      float4 mj4 = *reinterpret_cast<const float4*>(&Mk[j * 16 + quad * 4]);
      f32x4 init; init[0] = mj4.x; init[1] = mj4.y; init[2] = mj4.z; init[3] = mj4.w;
#pragma unroll
      for (int i = 0; i < 2; ++i) ST[j][i] = init;
      bf16x8 kf0 = *reinterpret_cast<const bf16x8*>(&Ks[(j * 16 + m16) * 64 + u0]);
      bf16x8 kf1 = *reinterpret_cast<const bf16x8*>(&Ks[(j * 16 + m16) * 64 + u1]);
#pragma unroll
      for (int i = 0; i < 2; ++i) {
        ST[j][i] = __builtin_amdgcn_mfma_f32_16x16x32_bf16(kf0, qf[i][0], ST[j][i], 0, 0, 0);
        ST[j][i] = __builtin_amdgcn_mfma_f32_16x16x32_bf16(kf1, qf[i][1], ST[j][i], 0, 0, 0);
      }
    }
    __builtin_amdgcn_s_setprio(0);

    // Softmax numerator + truncation pack + b64 spill into P (A-layout).
    const int kc_w = (quad >> 1);
    const int inner = (quad & 1) * 4;
#pragma unroll
    for (int j = 0; j < 4; ++j)
#pragma unroll
      for (int i = 0; i < 2; ++i) {
        float p0 = __builtin_amdgcn_exp2f(ST[j][i][0]);
        float p1 = __builtin_amdgcn_exp2f(ST[j][i][1]);
        float p2 = __builtin_amdgcn_exp2f(ST[j][i][2]);
        float p3 = __builtin_amdgcn_exp2f(ST[j][i][3]);
        uint2 pk;
        pk.x = __builtin_amdgcn_perm(__builtin_bit_cast(unsigned, p1),
                                     __builtin_bit_cast(unsigned, p0), 0x07060302u);
        pk.y = __builtin_amdgcn_perm(__builtin_bit_cast(unsigned, p3),
                                     __builtin_bit_cast(unsigned, p2), 0x07060302u);
        *reinterpret_cast<uint2*>(
            &U[wb + (j * 2 + kc_w) * 264 + (i * 16 + m16) * 8 + inner]) = pk;
      }
    asm volatile("s_waitcnt lgkmcnt(0)" ::: "memory");  // own-wave P RAW

    bf16x8 pf[2][2];
#pragma unroll
    for (int i = 0; i < 2; ++i)
#pragma unroll
      for (int s = 0; s < 2; ++s)
        pf[i][s] = *reinterpret_cast<const bf16x8*>(
            &U[wb + (s * 4 + quad) * 264 + (i * 16 + m16) * 8]);

    // l-accumulate via ones-MFMA: lacc rows == oacc rows (C-layout).
    __builtin_amdgcn_s_setprio(1);
#pragma unroll
    for (int i = 0; i < 2; ++i) {
      lacc[i] = __builtin_amdgcn_mfma_f32_16x16x32_bf16(pf[i][0], ones, lacc[i], 0, 0, 0);
      lacc[i] = __builtin_amdgcn_mfma_f32_16x16x32_bf16(pf[i][1], ones, lacc[i], 0, 0, 0);
    }

#pragma unroll
    for (int j = 0; j < 4; ++j) {
      bf16x8 vf0 = *reinterpret_cast<const bf16x8*>(&Vs[(j * 16 + m16) * 64 + u0]);
      bf16x8 vf1 = *reinterpret_cast<const bf16x8*>(&Vs[(j * 16 + m16) * 64 + u1]);
#pragma unroll
      for (int i = 0; i < 2; ++i) {
        oacc[i][j] = __builtin_amdgcn_mfma_f32_16x16x32_bf16(pf[i][0], vf0, oacc[i][j], 0, 0, 0);
        oacc[i][j] = __builtin_amdgcn_mfma_f32_16x16x32_bf16(pf[i][1], vf1, oacc[i][j], 0, 0, 0);
      }
    }
    __builtin_amdgcn_s_setprio(0);
    __syncthreads();
  }

#pragma unroll
  for (int i = 0; i < 2; ++i)
#pragma unroll
    for (int j = 0; j < 4; ++j) {
      int d = j * 16 + m16;
#pragma unroll
      for (int rg = 0; rg < 4; ++rg) {
        int ql = qb * 256 + w * 32 + i * 16 + quad * 4 + rg;
        Out[(b * kL + ql) * kE + h * kHD + d] =
            f2bf(oacc[i][j][rg] / lacc[i][rg]);
      }
    }
}

extern "C" void kernel_launch(void* const* d_in, const int* in_sizes, int n_in,
                              void* d_out, int out_size, void* d_ws, size_t ws_size,
                              hipStream_t stream) {
  const float* x  = (const float*)d_in[0];
  const int* mask = (const int*)d_in[1];
  const float* Wq = (const float*)d_in[2];
  const float* bq = (const float*)d_in[3];
  const float* Wk = (const float*)d_in[4];
  const float* bk = (const float*)d_in[5];
  const float* Wv = (const float*)d_in[6];
  const float* bv = (const float*)d_in[7];
  const float* Wo = (const float*)d_in[8];
  const float* bo = (const float*)d_in[9];

  short* ws  = (short*)d_ws;
  short* xb  = ws;                  // 8388608 shorts
  short* Wqb = xb  + 8388608;       // 4 x 1048576, contiguous
  short* Wkb = Wqb + 1048576;
  short* Wvb = Wkb + 1048576;
  short* Wob = Wvb + 1048576;
  short* Qb  = Wob + 1048576;       // 8388608 each
  short* Kb  = Qb  + 8388608;
  short* Vtb = Kb  + 8388608;
  short* AOb = Vtb + 8388608;       // doubles as Vl before attention runs
  float* Mkf = (float*)(AOb + 8388608);  // 8192 floats

  k_prep<<<12320, 256, 0, stream>>>(x, Wq, Wk, Wv, Wo, mask, xb, Wqb, Mkf);
  // V row-major into AOb (dead until attention runs), then transpose into Vtb.
  k_gemm_qkv<<<dim3(24, 32), 512, 0, stream>>>(xb, Wqb, Wkb, Wvb, bq, bk, bv, Qb, Kb, AOb);
  k_trv<<<dim3(32, 64), 256, 0, stream>>>(AOb, Vtb);
  k_attn<<<dim3(8, 64), 512, 0, stream>>>(Qb, Kb, Vtb, Mkf, AOb);
  k_gemm_out<<<dim3(8, 32), 512, 0, stream>>>(AOb, Wob, bo, (float*)d_out);
}

// Round 10
// 257.270 us; speedup vs baseline: 1.1051x; 1.0186x over previous
//
#include <hip/hip_runtime.h>
#include <hip/hip_bf16.h>

// Problem: B=4, L=2048, E=1024, H=16, HD=64.
// NOTE: the reference's _separate_heads is reshape(B,L,E)->(B,H,L,HD) with NO
// transpose: the flat (B,L,E) buffer IS the (B,H,L,HD) buffer. Within a batch
// flat idx lr*1024+e maps to h=lr>>7, l=(lr&127)*16+(e>>6), hd=e&63 -- the
// head comes from ROW bits. Hence: V transpose must stay a separate
// POSITIONAL pass (k_trv); a fused GEMM-epilogue V^T is wrong (R8 trap).
//
// R13/R14: staging request-granularity fix: total 334->266.
// R16/R17: attn 8 waves / 256 q-rows / block: attn 92.9->74.4us.
// R19: k_prep fusion (5 launches). 262.1us.
// R20: attn KVBLK 64->128: stage K[128x64]+Vt[64x128]+Mk[128] once, one
// barrier pair per 128 keys, two 64-key halves back-to-back (P region is
// wave-private -> reuse across halves is same-wave-DS-ordered, same
// discipline the loop already used across iterations). Mk staged by waves
// 0-1 only (was 8x redundant broadcast -> bank-conflict suspect). Barriers
// 64->32, staging instrs 96->80. LDS 66.5KB, still 2 blocks/CU.
namespace {
constexpr int kB = 4, kL = 2048, kE = 1024, kH = 16, kHD = 64;
constexpr float kCs = 0.18033688f;  // log2(e)/8, folded into Q projection
}

typedef __attribute__((ext_vector_type(8))) short bf16x8;
typedef __attribute__((ext_vector_type(4))) float f32x4;

__device__ __forceinline__ short f2bf(float f) {
  __hip_bfloat16 h = __float2bfloat16(f);
  return *reinterpret_cast<short*>(&h);
}

__device__ __forceinline__ void load_lds16(const void* g, void* l) {
  __builtin_amdgcn_global_load_lds((const __attribute__((address_space(1))) void*)g,
                                   (__attribute__((address_space(3))) void*)l, 16, 0, 0);
}
__device__ __forceinline__ void load_lds4(const void* g, void* l) {
  __builtin_amdgcn_global_load_lds((const __attribute__((address_space(1))) void*)g,
                                   (__attribute__((address_space(3))) void*)l, 4, 0, 0);
}

// Fused prep: x cast (blocks 0..8191), 4 weight casts (8192..12287),
// mask->float offsets (12288..12319). One dispatch.
__global__ __launch_bounds__(256) void k_prep(const float* __restrict__ x,
                                              const float* __restrict__ w0,
                                              const float* __restrict__ w1,
                                              const float* __restrict__ w2,
                                              const float* __restrict__ w3,
                                              const int* __restrict__ mask,
                                              short* __restrict__ xb,
                                              short* __restrict__ wdst,
                                              float* __restrict__ mkf) {
  const int bx = blockIdx.x;
  const int tid = threadIdx.x;
  if (bx < 8192) {
    int i = (bx * 256 + tid) * 4;
    float4 v = *reinterpret_cast<const float4*>(x + i);
    short4 o;
    o.x = f2bf(v.x); o.y = f2bf(v.y); o.z = f2bf(v.z); o.w = f2bf(v.w);
    *reinterpret_cast<short4*>(xb + i) = o;
  } else if (bx < 12288) {
    int b2 = bx - 8192;
    int seg = b2 >> 10;
    const float* s = seg == 0 ? w0 : seg == 1 ? w1 : seg == 2 ? w2 : w3;
    int local = ((b2 & 1023) * 256 + tid) * 4;
    float4 v = *reinterpret_cast<const float4*>(s + local);
    short4 o;
    o.x = f2bf(v.x); o.y = f2bf(v.y); o.z = f2bf(v.z); o.w = f2bf(v.w);
    *reinterpret_cast<short4*>(wdst + seg * 1048576 + local) = o;
  } else {
    int i = (bx - 12288) * 256 + tid;
    mkf[i] = mask[i] != 0 ? -10.0f : -1.0e10f;
  }
}

// Per-head V transpose: Vl[hb][l'][d] -> Vt[hb][d][l']. 64x64 tiles via LDS,
// both global sides coalesced. POSITIONAL on the flat buffer (see header).
__global__ __launch_bounds__(256) void k_trv(const short* __restrict__ Vl,
                                             short* __restrict__ Vt) {
  __shared__ unsigned T[64 * 33];
  const int t = threadIdx.x;
  const int hb = blockIdx.y;
  const int l0 = blockIdx.x * 64;
  const short* src = Vl + hb * 131072;
  short* dst = Vt + hb * 131072;
  const int d8 = (t & 7) * 8;
  const int lp = t >> 3;
  const uint4 va = *reinterpret_cast<const uint4*>(src + (l0 + 2 * lp) * 64 + d8);
  const uint4 vb = *reinterpret_cast<const uint4*>(src + (l0 + 2 * lp + 1) * 64 + d8);
  const unsigned a[4] = {va.x, va.y, va.z, va.w};
  const unsigned b[4] = {vb.x, vb.y, vb.z, vb.w};
#pragma unroll
  for (int j = 0; j < 4; ++j) {
    unsigned z0 = __builtin_amdgcn_perm(b[j], a[j], 0x05040100u);
    unsigned z1 = __builtin_amdgcn_perm(b[j], a[j], 0x07060302u);
    T[(d8 + 2 * j) * 33 + lp] = z0;
    T[(d8 + 2 * j + 1) * 33 + lp] = z1;
  }
  __syncthreads();
  const int u = (t & 7) * 4;
#pragma unroll
  for (int h2 = 0; h2 < 2; ++h2) {
    int d = (t >> 3) + h2 * 32;
    uint4 r;
    r.x = T[d * 33 + u];     r.y = T[d * 33 + u + 1];
    r.z = T[d * 33 + u + 2]; r.w = T[d * 33 + u + 3];
    *reinterpret_cast<uint4*>(dst + d * 2048 + l0 + u * 2) = r;
  }
}

// ---- deep-pipelined GEMM core: 256x128 tile, BK=64, 8 waves, ring-3 LDS ----
// (144 KiB), counted vmcnt(6) at K-tile boundaries, one barrier per K-tile.
// Staging: per instruction 8 rows x 128 B contiguous (full lines); LDS
// row-major [row][64] with source-side st-swizzle: LDS[r][s] = G[r][s^(r&7)];
// frag ds_read_b128 reads unit (quad+4s)^(m16&7) -> uniform slots (free).
struct GemmCore256 {
  f32x4 acc[4][4];
  int tid, w, lane, quad, m16, wm, wn;
  __device__ __forceinline__ void run(const short* __restrict__ A,
                                      const short* __restrict__ W,
                                      int bm0, int bn0, short* S) {
    tid = threadIdx.x;
    w = tid >> 6; lane = tid & 63; quad = lane >> 4; m16 = lane & 15;
    wm = (w >> 1) * 64; wn = (w & 1) * 64;   // 4 M-waves x 2 N-waves, 64x64 each
#pragma unroll
    for (int i = 0; i < 4; ++i)
#pragma unroll
      for (int j = 0; j < 4; ++j) acc[i][j] = (f32x4){0, 0, 0, 0};

    const int srow = tid >> 3;
    const int sunit = (tid & 7) ^ (srow & 7);
    const short* Ag = A + (bm0 + srow) * 1024 + sunit * 8;
    const short* Wg = W + (bn0 + srow) * 1024 + sunit * 8;
    const int x7 = m16 & 7;
    const int u0 = (quad ^ x7) * 8;   // s=0
    const int u1 = u0 ^ 32;           // s=1
    const int baseA = (wm + m16) * 64;
    const int baseB = 16384 + (wn + m16) * 64;

#define STG_A(Sb, T, c) load_lds16(Ag + (c) * 65536 + (T) * 64, (Sb) + (c) * 4096 + tid * 8)
#define STG_B(Sb, T, c) load_lds16(Wg + (c) * 65536 + (T) * 64, (Sb) + 16384 + (c) * 4096 + tid * 8)

    // Prologue: stage K-tiles 0 (buf0) and 1 (buf1); wait for tile 0 only.
    short* S1 = S + 24576;
    STG_A(S, 0, 0); STG_A(S, 0, 1); STG_A(S, 0, 2); STG_A(S, 0, 3);
    STG_B(S, 0, 0); STG_B(S, 0, 1);
    STG_A(S1, 1, 0); STG_A(S1, 1, 1); STG_A(S1, 1, 2); STG_A(S1, 1, 3);
    STG_B(S1, 1, 0); STG_B(S1, 1, 1);
    asm volatile("s_waitcnt vmcnt(6)" ::: "memory");
    __builtin_amdgcn_s_barrier();
    __builtin_amdgcn_sched_barrier(0);

    int bc = 0;
    for (int t = 0; t < 16; ++t) {
      short* Sc = S + bc * 24576;
      int b2 = bc + 2; if (b2 >= 3) b2 -= 3;
      short* Sp = S + b2 * 24576;
      const bool pf = (t < 14);  // tile t+2 exists

      bf16x8 a[4][2], b[4][2];
#pragma unroll
      for (int i = 0; i < 4; ++i) {
        a[i][0] = *reinterpret_cast<const bf16x8*>(&Sc[baseA + i * 1024 + u0]);
        a[i][1] = *reinterpret_cast<const bf16x8*>(&Sc[baseA + i * 1024 + u1]);
      }
#pragma unroll
      for (int j = 0; j < 4; ++j) {
        b[j][0] = *reinterpret_cast<const bf16x8*>(&Sc[baseB + j * 1024 + u0]);
        b[j][1] = *reinterpret_cast<const bf16x8*>(&Sc[baseB + j * 1024 + u1]);
      }
      if (pf) {
        STG_A(Sp, t + 2, 0); STG_A(Sp, t + 2, 1); STG_A(Sp, t + 2, 2); STG_A(Sp, t + 2, 3);
        STG_B(Sp, t + 2, 0); STG_B(Sp, t + 2, 1);
      }
      __builtin_amdgcn_s_setprio(1);
#pragma unroll
      for (int i = 0; i < 4; ++i)
#pragma unroll
        for (int j = 0; j < 4; ++j) {
          acc[i][j] = __builtin_amdgcn_mfma_f32_16x16x32_bf16(a[i][0], b[j][0], acc[i][j], 0, 0, 0);
          acc[i][j] = __builtin_amdgcn_mfma_f32_16x16x32_bf16(a[i][1], b[j][1], acc[i][j], 0, 0, 0);
        }
      __builtin_amdgcn_s_setprio(0);
      if (pf) { asm volatile("s_waitcnt vmcnt(6)" ::: "memory"); }
      else    { asm volatile("s_waitcnt vmcnt(0)" ::: "memory"); }
      __builtin_amdgcn_s_barrier();
      __builtin_amdgcn_sched_barrier(0);
      bc += 1; if (bc >= 3) bc -= 3;
    }
#undef STG_A
#undef STG_B
  }
};

// Fused Q/K/V projection, XCD-swizzled: 768 blocks = 3 exact full rounds of
// 256 CUs at 1 block/CU (144 KiB LDS). 4 row-panels/XCD -> 2 MB A working
// set per XCD (L2-resident); all 24 col-blocks of a panel on the same XCD.
__global__ __launch_bounds__(512, 2) void k_gemm_qkv(const short* __restrict__ xb,
                                                     const short* __restrict__ Wq,
                                                     const short* __restrict__ Wk,
                                                     const short* __restrict__ Wv,
                                                     const float* __restrict__ bq,
                                                     const float* __restrict__ bk,
                                                     const float* __restrict__ bv,
                                                     short* __restrict__ Q,
                                                     short* __restrict__ K,
                                                     short* __restrict__ Vl) {
  __shared__ __attribute__((aligned(16))) short S[73728];  // 144 KiB, ring-3
  const int l = blockIdx.x + 24 * blockIdx.y;  // 0..767
  const int xcd = l & 7, wv_ = l >> 3;         // wv_: 0..95
  const int bm0 = (xcd + 8 * (wv_ & 3)) * 256;
  const int colsel = wv_ >> 2;                 // 0..23
  const int sel = colsel >> 3;
  const int bn0 = (colsel & 7) * 128;
  const short* W = sel == 0 ? Wq : sel == 1 ? Wk : Wv;
  const float* bias = sel == 0 ? bq : sel == 1 ? bk : bv;

  GemmCore256 g;
  g.run(xb, W, bm0, bn0, S);

  float bj[4];
#pragma unroll
  for (int j = 0; j < 4; ++j) bj[j] = bias[bn0 + g.wn + j * 16 + g.m16];

  short* C = sel == 0 ? Q : sel == 1 ? K : Vl;
  float sc = sel == 0 ? kCs : 1.0f;
#pragma unroll
  for (int i = 0; i < 4; ++i)
#pragma unroll
    for (int j = 0; j < 4; ++j)
#pragma unroll
      for (int rg = 0; rg < 4; ++rg) {
        int row = bm0 + g.wm + i * 16 + g.quad * 4 + rg;
        int col = bn0 + g.wn + j * 16 + g.m16;
        C[row * 1024 + col] = f2bf((g.acc[i][j][rg] + bj[j]) * sc);
      }
}

// Output projection: fp32 row-major out. 256 blocks = 1 exact full round.
__global__ __launch_bounds__(512, 2) void k_gemm_out(const short* __restrict__ A,
                                                     const short* __restrict__ Wo,
                                                     const float* __restrict__ bo,
                                                     float* __restrict__ C) {
  __shared__ __attribute__((aligned(16))) short S[73728];
  const int l = blockIdx.x + 8 * blockIdx.y;  // 0..255
  const int xcd = l & 7, wv_ = l >> 3;        // wv_: 0..31
  const int bm0 = (xcd + 8 * (wv_ & 3)) * 256;
  const int bn0 = (wv_ >> 2) * 128;
  GemmCore256 g;
  g.run(A, Wo, bm0, bn0, S);
  float bj[4];
#pragma unroll
  for (int j = 0; j < 4; ++j) bj[j] = bo[bn0 + g.wn + j * 16 + g.m16];
#pragma unroll
  for (int i = 0; i < 4; ++i)
#pragma unroll
    for (int j = 0; j < 4; ++j)
#pragma unroll
      for (int rg = 0; rg < 4; ++rg) {
        int row = bm0 + g.wm + i * 16 + g.quad * 4 + rg;
        int col = bn0 + g.wn + j * 16 + g.m16;
        C[row * 1024 + col] = g.acc[i][j][rg] + bj[j];
      }
}

// Flash-style attention, S^T formulation. 8 waves / 256 q-rows / block.
// R20: KVBLK=128 -- stage K[128x64]+Vt[64x128]+Mk[128] once per barrier
// pair, compute the two 64-key halves back-to-back. P region is wave-
// private (wb): reuse across halves relies on same-wave DS ordering +
// lgkmcnt(0), identical to the existing cross-iteration discipline.
__global__ __launch_bounds__(512, 4) void k_attn(const short* __restrict__ Q,
                                                 const short* __restrict__ Km,
                                                 const short* __restrict__ Vt,
                                                 const float* __restrict__ Mg,
                                                 short* __restrict__ Out) {
  __shared__ __attribute__((aligned(16))) short U[16896];  // Qs(16384) / Ps(8x2112) alias
  __shared__ __attribute__((aligned(16))) short Ks[8192];  // [128 rows][64], swizzled
  __shared__ __attribute__((aligned(16))) short Vs[8192];  // [64 d][128 keys], swizzled
  __shared__ __attribute__((aligned(16))) float Mk[128];

  const int tid = threadIdx.x;
  const int w = tid >> 6, lane = tid & 63;
  const int quad = lane >> 4, m16 = lane & 15;
  const int lid = blockIdx.x + 8 * blockIdx.y;   // 0..511
  const int xcd = lid & 7, wv_ = lid >> 3;       // wv_: 0..63
  const int hb = xcd + 8 * (wv_ & 7);
  const int qb = wv_ >> 3;                       // 0..7
  const int b = hb >> 4, h = hb & 15;
  const int wb = w * 2112;

  const short* Qh = Q + hb * (kL * kHD) + qb * 256 * kHD;
  const short* Kh = Km + hb * (kL * kHD);
  const short* Vh = Vt + hb * (kL * kHD);
  const float* Mb = Mg + b * kL;

  // K/Q staging map: row = tid>>3 (0..63), 16B-unit = (tid&7)^(row&7).
  const int srow = tid >> 3;
  const int sunit = (tid & 7) ^ (srow & 7);
  // V staging map (256B rows): row = tid>>4 (0..31), unit = (tid&15)^(row&7).
  const int vr = tid >> 4;
  const int vu = (tid & 15) ^ (vr & 7);
  const int x7 = m16 & 7;
  const int u0 = (quad ^ x7) * 8;
  const int u1 = u0 ^ 32;

#pragma unroll
  for (int c = 0; c < 4; ++c)
    load_lds16(Qh + (c * 64 + srow) * 64 + sunit * 8, &U[c * 4096 + tid * 8]);
  __syncthreads();
  bf16x8 qf[2][2];
#pragma unroll
  for (int i = 0; i < 2; ++i) {
    qf[i][0] = *reinterpret_cast<const bf16x8*>(&U[(w * 32 + i * 16 + m16) * 64 + u0]);
    qf[i][1] = *reinterpret_cast<const bf16x8*>(&U[(w * 32 + i * 16 + m16) * 64 + u1]);
  }

  bf16x8 ones;
#pragma unroll
  for (int e = 0; e < 8; ++e) ones[e] = (short)0x3F80;  // bf16 1.0

  f32x4 oacc[2][4] = {};
  f32x4 lacc[2] = {};

  for (int kt = 0; kt < 16; ++kt) {
    const int kbase = kt * 128;
    // Stage 128 keys: K 2 instrs, V^T 2 instrs, Mk by waves 0-1 only.
    load_lds16(Kh + (kbase + srow) * 64 + sunit * 8, &Ks[tid * 8]);
    load_lds16(Kh + (kbase + 64 + srow) * 64 + sunit * 8, &Ks[4096 + tid * 8]);
    load_lds16(Vh + vr * 2048 + kbase + vu * 8, &Vs[tid * 8]);
    load_lds16(Vh + (32 + vr) * 2048 + kbase + vu * 8, &Vs[4096 + tid * 8]);
    if (tid < 128) load_lds4(Mb + kbase + tid, &Mk[tid]);
    __syncthreads();  // also orders all waves' qf reads before iter-0 Ps writes

#pragma unroll
    for (int hf = 0; hf < 2; ++hf) {
      // S^T tiles: ST[j][i], j = key-tile (rows), i = q-tile (cols).
      f32x4 ST[4][2];
      __builtin_amdgcn_s_setprio(1);
#pragma unroll
      for (int j = 0; j < 4; ++j) {
        float4 mj4 = *reinterpret_cast<const float4*>(&Mk[hf * 64 + j * 16 + quad * 4]);
        f32x4 init; init[0] = mj4.x; init[1] = mj4.y; init[2] = mj4.z; init[3] = mj4.w;
#pragma unroll
        for (int i = 0; i < 2; ++i) ST[j][i] = init;
        bf16x8 kf0 = *reinterpret_cast<const bf16x8*>(
            &Ks[hf * 4096 + (j * 16 + m16) * 64 + u0]);
        bf16x8 kf1 = *reinterpret_cast<const bf16x8*>(
            &Ks[hf * 4096 + (j * 16 + m16) * 64 + u1]);
#pragma unroll
        for (int i = 0; i < 2; ++i) {
          ST[j][i] = __builtin_amdgcn_mfma_f32_16x16x32_bf16(kf0, qf[i][0], ST[j][i], 0, 0, 0);
          ST[j][i] = __builtin_amdgcn_mfma_f32_16x16x32_bf16(kf1, qf[i][1], ST[j][i], 0, 0, 0);
        }
      }
      __builtin_amdgcn_s_setprio(0);

      // Softmax numerator + truncation pack + b64 spill into P (A-layout).
      const int kc_w = (quad >> 1);
      const int inner = (quad & 1) * 4;
#pragma unroll
      for (int j = 0; j < 4; ++j)
#pragma unroll
        for (int i = 0; i < 2; ++i) {
          float p0 = __builtin_amdgcn_exp2f(ST[j][i][0]);
          float p1 = __builtin_amdgcn_exp2f(ST[j][i][1]);
          float p2 = __builtin_amdgcn_exp2f(ST[j][i][2]);
          float p3 = __builtin_amdgcn_exp2f(ST[j][i][3]);
          uint2 pk;
          pk.x = __builtin_amdgcn_perm(__builtin_bit_cast(unsigned, p1),
                                       __builtin_bit_cast(unsigned, p0), 0x07060302u);
          pk.y = __builtin_amdgcn_perm(__builtin_bit_cast(unsigned, p3),
                                       __builtin_bit_cast(unsigned, p2), 0x07060302u);
          *reinterpret_cast<uint2*>(
              &U[wb + (j * 2 + kc_w) * 264 + (i * 16 + m16) * 8 + inner]) = pk;
        }
      asm volatile("s_waitcnt lgkmcnt(0)" ::: "memory");  // own-wave P RAW

      bf16x8 pf[2][2];
#pragma unroll
      for (int i = 0; i < 2; ++i)
#pragma unroll
        for (int s = 0; s < 2; ++s)
          pf[i][s] = *reinterpret_cast<const bf16x8*>(
              &U[wb + (s * 4 + quad) * 264 + (i * 16 + m16) * 8]);

      // l-accumulate via ones-MFMA: lacc rows == oacc rows (C-layout).
      __builtin_amdgcn_s_setprio(1);
#pragma unroll
      for (int i = 0; i < 2; ++i) {
        lacc[i] = __builtin_amdgcn_mfma_f32_16x16x32_bf16(pf[i][0], ones, lacc[i], 0, 0, 0);
        lacc[i] = __builtin_amdgcn_mfma_f32_16x16x32_bf16(pf[i][1], ones, lacc[i], 0, 0, 0);
      }

#pragma unroll
      for (int j = 0; j < 4; ++j) {
        // V^T row d = j*16+m16 has 16 units; G-unit for (half hf, k-slot s,
        // quad) = hf*8 + s*4 + quad; read swizzled unit = g ^ (d&7).
        bf16x8 vf0 = *reinterpret_cast<const bf16x8*>(
            &Vs[(j * 16 + m16) * 128 + ((hf * 8 + quad) ^ x7) * 8]);
        bf16x8 vf1 = *reinterpret_cast<const bf16x8*>(
            &Vs[(j * 16 + m16) * 128 + ((hf * 8 + 4 + quad) ^ x7) * 8]);
#pragma unroll
        for (int i = 0; i < 2; ++i) {
          oacc[i][j] = __builtin_amdgcn_mfma_f32_16x16x32_bf16(pf[i][0], vf0, oacc[i][j], 0, 0, 0);
          oacc[i][j] = __builtin_amdgcn_mfma_f32_16x16x32_bf16(pf[i][1], vf1, oacc[i][j], 0, 0, 0);
        }
      }
      __builtin_amdgcn_s_setprio(0);
    }
    __syncthreads();
  }

#pragma unroll
  for (int i = 0; i < 2; ++i)
#pragma unroll
    for (int j = 0; j < 4; ++j) {
      int d = j * 16 + m16;
#pragma unroll
      for (int rg = 0; rg < 4; ++rg) {
        int ql = qb * 256 + w * 32 + i * 16 + quad * 4 + rg;
        Out[(b * kL + ql) * kE + h * kHD + d] =
            f2bf(oacc[i][j][rg] / lacc[i][rg]);
      }
    }
}

extern "C" void kernel_launch(void* const* d_in, const int* in_sizes, int n_in,
                              void* d_out, int out_size, void* d_ws, size_t ws_size,
                              hipStream_t stream) {
  const float* x  = (const float*)d_in[0];
  const int* mask = (const int*)d_in[1];
  const float* Wq = (const float*)d_in[2];
  const float* bq = (const float*)d_in[3];
  const float* Wk = (const float*)d_in[4];
  const float* bk = (const float*)d_in[5];
  const float* Wv = (const float*)d_in[6];
  const float* bv = (const float*)d_in[7];
  const float* Wo = (const float*)d_in[8];
  const float* bo = (const float*)d_in[9];

  short* ws  = (short*)d_ws;
  short* xb  = ws;                  // 8388608 shorts
  short* Wqb = xb  + 8388608;       // 4 x 1048576, contiguous
  short* Wkb = Wqb + 1048576;
  short* Wvb = Wkb + 1048576;
  short* Wob = Wvb + 1048576;
  short* Qb  = Wob + 1048576;       // 8388608 each
  short* Kb  = Qb  + 8388608;
  short* Vtb = Kb  + 8388608;
  short* AOb = Vtb + 8388608;       // doubles as Vl before attention runs
  float* Mkf = (float*)(AOb + 8388608);  // 8192 floats

  k_prep<<<12320, 256, 0, stream>>>(x, Wq, Wk, Wv, Wo, mask, xb, Wqb, Mkf);
  // V row-major into AOb (dead until attention runs), then transpose into Vtb.
  k_gemm_qkv<<<dim3(24, 32), 512, 0, stream>>>(xb, Wqb, Wkb, Wvb, bq, bk, bv, Qb, Kb, AOb);
  k_trv<<<dim3(32, 64), 256, 0, stream>>>(AOb, Vtb);
  k_attn<<<dim3(8, 64), 512, 0, stream>>>(Qb, Kb, Vtb, Mkf, AOb);
  k_gemm_out<<<dim3(8, 32), 512, 0, stream>>>(AOb, Wob, bo, (float*)d_out);
}

// Round 11
// 252.115 us; speedup vs baseline: 1.1277x; 1.0204x over previous
//
#include <hip/hip_runtime.h>
#include <hip/hip_bf16.h>

// Problem: B=4, L=2048, E=1024, H=16, HD=64.
// NOTE: the reference's _separate_heads is reshape(B,L,E)->(B,H,L,HD) with NO
// transpose: the flat (B,L,E) buffer IS the (B,H,L,HD) buffer. Within a batch
// flat idx lr*1024+e maps to h=lr>>7, l=(lr&127)*16+(e>>6), hd=e&63 -- the
// head comes from ROW bits. Hence: V transpose must stay a separate
// POSITIONAL pass (k_trv); a fused GEMM-epilogue V^T is wrong (R8 trap).
//
// R13/R14: staging request-granularity fix: total 334->266.
// R16/R17: attn 8 waves / 256 q-rows / block, KVBLK=64: attn 74.4-75.9us.
// R19: k_prep fusion (5 launches). 262.1us.
// R20: KVBLK=128 REGRESSED attn (75.9->84.2, conflicts 6.29M->10.49M).
// R21: revert attn to R17 KVBLK=64; single rider: Mk staged by wave 0 only
// (was 8x-redundant broadcast -- A/B test for the 6.29M conflict source).
namespace {
constexpr int kB = 4, kL = 2048, kE = 1024, kH = 16, kHD = 64;
constexpr float kCs = 0.18033688f;  // log2(e)/8, folded into Q projection
}

typedef __attribute__((ext_vector_type(8))) short bf16x8;
typedef __attribute__((ext_vector_type(4))) float f32x4;

__device__ __forceinline__ short f2bf(float f) {
  __hip_bfloat16 h = __float2bfloat16(f);
  return *reinterpret_cast<short*>(&h);
}

__device__ __forceinline__ void load_lds16(const void* g, void* l) {
  __builtin_amdgcn_global_load_lds((const __attribute__((address_space(1))) void*)g,
                                   (__attribute__((address_space(3))) void*)l, 16, 0, 0);
}
__device__ __forceinline__ void load_lds4(const void* g, void* l) {
  __builtin_amdgcn_global_load_lds((const __attribute__((address_space(1))) void*)g,
                                   (__attribute__((address_space(3))) void*)l, 4, 0, 0);
}

// Fused prep: x cast (blocks 0..8191), 4 weight casts (8192..12287),
// mask->float offsets (12288..12319). One dispatch.
__global__ __launch_bounds__(256) void k_prep(const float* __restrict__ x,
                                              const float* __restrict__ w0,
                                              const float* __restrict__ w1,
                                              const float* __restrict__ w2,
                                              const float* __restrict__ w3,
                                              const int* __restrict__ mask,
                                              short* __restrict__ xb,
                                              short* __restrict__ wdst,
                                              float* __restrict__ mkf) {
  const int bx = blockIdx.x;
  const int tid = threadIdx.x;
  if (bx < 8192) {
    int i = (bx * 256 + tid) * 4;
    float4 v = *reinterpret_cast<const float4*>(x + i);
    short4 o;
    o.x = f2bf(v.x); o.y = f2bf(v.y); o.z = f2bf(v.z); o.w = f2bf(v.w);
    *reinterpret_cast<short4*>(xb + i) = o;
  } else if (bx < 12288) {
    int b2 = bx - 8192;
    int seg = b2 >> 10;
    const float* s = seg == 0 ? w0 : seg == 1 ? w1 : seg == 2 ? w2 : w3;
    int local = ((b2 & 1023) * 256 + tid) * 4;
    float4 v = *reinterpret_cast<const float4*>(s + local);
    short4 o;
    o.x = f2bf(v.x); o.y = f2bf(v.y); o.z = f2bf(v.z); o.w = f2bf(v.w);
    *reinterpret_cast<short4*>(wdst + seg * 1048576 + local) = o;
  } else {
    int i = (bx - 12288) * 256 + tid;
    mkf[i] = mask[i] != 0 ? -10.0f : -1.0e10f;
  }
}

// Per-head V transpose: Vl[hb][l'][d] -> Vt[hb][d][l']. 64x64 tiles via LDS,
// both global sides coalesced. POSITIONAL on the flat buffer (see header).
__global__ __launch_bounds__(256) void k_trv(const short* __restrict__ Vl,
                                             short* __restrict__ Vt) {
  __shared__ unsigned T[64 * 33];
  const int t = threadIdx.x;
  const int hb = blockIdx.y;
  const int l0 = blockIdx.x * 64;
  const short* src = Vl + hb * 131072;
  short* dst = Vt + hb * 131072;
  const int d8 = (t & 7) * 8;
  const int lp = t >> 3;
  const uint4 va = *reinterpret_cast<const uint4*>(src + (l0 + 2 * lp) * 64 + d8);
  const uint4 vb = *reinterpret_cast<const uint4*>(src + (l0 + 2 * lp + 1) * 64 + d8);
  const unsigned a[4] = {va.x, va.y, va.z, va.w};
  const unsigned b[4] = {vb.x, vb.y, vb.z, vb.w};
#pragma unroll
  for (int j = 0; j < 4; ++j) {
    unsigned z0 = __builtin_amdgcn_perm(b[j], a[j], 0x05040100u);
    unsigned z1 = __builtin_amdgcn_perm(b[j], a[j], 0x07060302u);
    T[(d8 + 2 * j) * 33 + lp] = z0;
    T[(d8 + 2 * j + 1) * 33 + lp] = z1;
  }
  __syncthreads();
  const int u = (t & 7) * 4;
#pragma unroll
  for (int h2 = 0; h2 < 2; ++h2) {
    int d = (t >> 3) + h2 * 32;
    uint4 r;
    r.x = T[d * 33 + u];     r.y = T[d * 33 + u + 1];
    r.z = T[d * 33 + u + 2]; r.w = T[d * 33 + u + 3];
    *reinterpret_cast<uint4*>(dst + d * 2048 + l0 + u * 2) = r;
  }
}

// ---- deep-pipelined GEMM core: 256x128 tile, BK=64, 8 waves, ring-3 LDS ----
// (144 KiB), counted vmcnt(6) at K-tile boundaries, one barrier per K-tile.
// Staging: per instruction 8 rows x 128 B contiguous (full lines); LDS
// row-major [row][64] with source-side st-swizzle: LDS[r][s] = G[r][s^(r&7)];
// frag ds_read_b128 reads unit (quad+4s)^(m16&7) -> uniform slots (free).
struct GemmCore256 {
  f32x4 acc[4][4];
  int tid, w, lane, quad, m16, wm, wn;
  __device__ __forceinline__ void run(const short* __restrict__ A,
                                      const short* __restrict__ W,
                                      int bm0, int bn0, short* S) {
    tid = threadIdx.x;
    w = tid >> 6; lane = tid & 63; quad = lane >> 4; m16 = lane & 15;
    wm = (w >> 1) * 64; wn = (w & 1) * 64;   // 4 M-waves x 2 N-waves, 64x64 each
#pragma unroll
    for (int i = 0; i < 4; ++i)
#pragma unroll
      for (int j = 0; j < 4; ++j) acc[i][j] = (f32x4){0, 0, 0, 0};

    const int srow = tid >> 3;
    const int sunit = (tid & 7) ^ (srow & 7);
    const short* Ag = A + (bm0 + srow) * 1024 + sunit * 8;
    const short* Wg = W + (bn0 + srow) * 1024 + sunit * 8;
    const int x7 = m16 & 7;
    const int u0 = (quad ^ x7) * 8;   // s=0
    const int u1 = u0 ^ 32;           // s=1
    const int baseA = (wm + m16) * 64;
    const int baseB = 16384 + (wn + m16) * 64;

#define STG_A(Sb, T, c) load_lds16(Ag + (c) * 65536 + (T) * 64, (Sb) + (c) * 4096 + tid * 8)
#define STG_B(Sb, T, c) load_lds16(Wg + (c) * 65536 + (T) * 64, (Sb) + 16384 + (c) * 4096 + tid * 8)

    // Prologue: stage K-tiles 0 (buf0) and 1 (buf1); wait for tile 0 only.
    short* S1 = S + 24576;
    STG_A(S, 0, 0); STG_A(S, 0, 1); STG_A(S, 0, 2); STG_A(S, 0, 3);
    STG_B(S, 0, 0); STG_B(S, 0, 1);
    STG_A(S1, 1, 0); STG_A(S1, 1, 1); STG_A(S1, 1, 2); STG_A(S1, 1, 3);
    STG_B(S1, 1, 0); STG_B(S1, 1, 1);
    asm volatile("s_waitcnt vmcnt(6)" ::: "memory");
    __builtin_amdgcn_s_barrier();
    __builtin_amdgcn_sched_barrier(0);

    int bc = 0;
    for (int t = 0; t < 16; ++t) {
      short* Sc = S + bc * 24576;
      int b2 = bc + 2; if (b2 >= 3) b2 -= 3;
      short* Sp = S + b2 * 24576;
      const bool pf = (t < 14);  // tile t+2 exists

      bf16x8 a[4][2], b[4][2];
#pragma unroll
      for (int i = 0; i < 4; ++i) {
        a[i][0] = *reinterpret_cast<const bf16x8*>(&Sc[baseA + i * 1024 + u0]);
        a[i][1] = *reinterpret_cast<const bf16x8*>(&Sc[baseA + i * 1024 + u1]);
      }
#pragma unroll
      for (int j = 0; j < 4; ++j) {
        b[j][0] = *reinterpret_cast<const bf16x8*>(&Sc[baseB + j * 1024 + u0]);
        b[j][1] = *reinterpret_cast<const bf16x8*>(&Sc[baseB + j * 1024 + u1]);
      }
      if (pf) {
        STG_A(Sp, t + 2, 0); STG_A(Sp, t + 2, 1); STG_A(Sp, t + 2, 2); STG_A(Sp, t + 2, 3);
        STG_B(Sp, t + 2, 0); STG_B(Sp, t + 2, 1);
      }
      __builtin_amdgcn_s_setprio(1);
#pragma unroll
      for (int i = 0; i < 4; ++i)
#pragma unroll
        for (int j = 0; j < 4; ++j) {
          acc[i][j] = __builtin_amdgcn_mfma_f32_16x16x32_bf16(a[i][0], b[j][0], acc[i][j], 0, 0, 0);
          acc[i][j] = __builtin_amdgcn_mfma_f32_16x16x32_bf16(a[i][1], b[j][1], acc[i][j], 0, 0, 0);
        }
      __builtin_amdgcn_s_setprio(0);
      if (pf) { asm volatile("s_waitcnt vmcnt(6)" ::: "memory"); }
      else    { asm volatile("s_waitcnt vmcnt(0)" ::: "memory"); }
      __builtin_amdgcn_s_barrier();
      __builtin_amdgcn_sched_barrier(0);
      bc += 1; if (bc >= 3) bc -= 3;
    }
#undef STG_A
#undef STG_B
  }
};

// Fused Q/K/V projection, XCD-swizzled: 768 blocks = 3 exact full rounds of
// 256 CUs at 1 block/CU (144 KiB LDS). 4 row-panels/XCD -> 2 MB A working
// set per XCD (L2-resident); all 24 col-blocks of a panel on the same XCD.
__global__ __launch_bounds__(512, 2) void k_gemm_qkv(const short* __restrict__ xb,
                                                     const short* __restrict__ Wq,
                                                     const short* __restrict__ Wk,
                                                     const short* __restrict__ Wv,
                                                     const float* __restrict__ bq,
                                                     const float* __restrict__ bk,
                                                     const float* __restrict__ bv,
                                                     short* __restrict__ Q,
                                                     short* __restrict__ K,
                                                     short* __restrict__ Vl) {
  __shared__ __attribute__((aligned(16))) short S[73728];  // 144 KiB, ring-3
  const int l = blockIdx.x + 24 * blockIdx.y;  // 0..767
  const int xcd = l & 7, wv_ = l >> 3;         // wv_: 0..95
  const int bm0 = (xcd + 8 * (wv_ & 3)) * 256;
  const int colsel = wv_ >> 2;                 // 0..23
  const int sel = colsel >> 3;
  const int bn0 = (colsel & 7) * 128;
  const short* W = sel == 0 ? Wq : sel == 1 ? Wk : Wv;
  const float* bias = sel == 0 ? bq : sel == 1 ? bk : bv;

  GemmCore256 g;
  g.run(xb, W, bm0, bn0, S);

  float bj[4];
#pragma unroll
  for (int j = 0; j < 4; ++j) bj[j] = bias[bn0 + g.wn + j * 16 + g.m16];

  short* C = sel == 0 ? Q : sel == 1 ? K : Vl;
  float sc = sel == 0 ? kCs : 1.0f;
#pragma unroll
  for (int i = 0; i < 4; ++i)
#pragma unroll
    for (int j = 0; j < 4; ++j)
#pragma unroll
      for (int rg = 0; rg < 4; ++rg) {
        int row = bm0 + g.wm + i * 16 + g.quad * 4 + rg;
        int col = bn0 + g.wn + j * 16 + g.m16;
        C[row * 1024 + col] = f2bf((g.acc[i][j][rg] + bj[j]) * sc);
      }
}

// Output projection: fp32 row-major out. 256 blocks = 1 exact full round.
__global__ __launch_bounds__(512, 2) void k_gemm_out(const short* __restrict__ A,
                                                     const short* __restrict__ Wo,
                                                     const float* __restrict__ bo,
                                                     float* __restrict__ C) {
  __shared__ __attribute__((aligned(16))) short S[73728];
  const int l = blockIdx.x + 8 * blockIdx.y;  // 0..255
  const int xcd = l & 7, wv_ = l >> 3;        // wv_: 0..31
  const int bm0 = (xcd + 8 * (wv_ & 3)) * 256;
  const int bn0 = (wv_ >> 2) * 128;
  GemmCore256 g;
  g.run(A, Wo, bm0, bn0, S);
  float bj[4];
#pragma unroll
  for (int j = 0; j < 4; ++j) bj[j] = bo[bn0 + g.wn + j * 16 + g.m16];
#pragma unroll
  for (int i = 0; i < 4; ++i)
#pragma unroll
    for (int j = 0; j < 4; ++j)
#pragma unroll
      for (int rg = 0; rg < 4; ++rg) {
        int row = bm0 + g.wm + i * 16 + g.quad * 4 + rg;
        int col = bn0 + g.wn + j * 16 + g.m16;
        C[row * 1024 + col] = g.acc[i][j][rg] + bj[j];
      }
}

// Flash-style attention, S^T formulation. 8 waves / 256 q-rows / block.
// KVBLK=64 (R17 proven structure). Stage -> sync -> compute -> sync, single
// buffer (TLP hides latency). Full-line staging w/ source-side st-swizzle.
// R21: Mk staged by wave 0 only (dedup 8x redundant broadcast).
__global__ __launch_bounds__(512, 4) void k_attn(const short* __restrict__ Q,
                                                 const short* __restrict__ Km,
                                                 const short* __restrict__ Vt,
                                                 const float* __restrict__ Mg,
                                                 short* __restrict__ Out) {
  __shared__ __attribute__((aligned(16))) short U[16896];  // Qs(16384) / Ps(8x2112) alias
  __shared__ __attribute__((aligned(16))) short Ks[4096];  // 64x64, swizzled
  __shared__ __attribute__((aligned(16))) short Vs[4096];  // 64 d-rows x 64 keys
  __shared__ __attribute__((aligned(16))) float Mk[64];

  const int tid = threadIdx.x;
  const int w = tid >> 6, lane = tid & 63;
  const int quad = lane >> 4, m16 = lane & 15;
  const int lid = blockIdx.x + 8 * blockIdx.y;   // 0..511
  const int xcd = lid & 7, wv_ = lid >> 3;       // wv_: 0..63
  const int hb = xcd + 8 * (wv_ & 7);
  const int qb = wv_ >> 3;                       // 0..7
  const int b = hb >> 4, h = hb & 15;
  const int wb = w * 2112;

  const short* Qh = Q + hb * (kL * kHD) + qb * 256 * kHD;
  const short* Kh = Km + hb * (kL * kHD);
  const short* Vh = Vt + hb * (kL * kHD);
  const float* Mb = Mg + b * kL;

  const int srow = tid >> 3;
  const int sunit = (tid & 7) ^ (srow & 7);
  const int x7 = m16 & 7;
  const int u0 = (quad ^ x7) * 8;
  const int u1 = u0 ^ 32;

#pragma unroll
  for (int c = 0; c < 4; ++c)
    load_lds16(Qh + (c * 64 + srow) * 64 + sunit * 8, &U[c * 4096 + tid * 8]);
  __syncthreads();
  bf16x8 qf[2][2];
#pragma unroll
  for (int i = 0; i < 2; ++i) {
    qf[i][0] = *reinterpret_cast<const bf16x8*>(&U[(w * 32 + i * 16 + m16) * 64 + u0]);
    qf[i][1] = *reinterpret_cast<const bf16x8*>(&U[(w * 32 + i * 16 + m16) * 64 + u1]);
  }

  bf16x8 ones;
#pragma unroll
  for (int e = 0; e < 8; ++e) ones[e] = (short)0x3F80;  // bf16 1.0

  f32x4 oacc[2][4] = {};
  f32x4 lacc[2] = {};

  for (int kb = 0; kb < 32; ++kb) {
    int kbase = kb * 64;
    load_lds16(Kh + (kbase + srow) * 64 + sunit * 8, &Ks[tid * 8]);
    load_lds16(Vh + srow * 2048 + kbase + sunit * 8, &Vs[tid * 8]);
    if (tid < 64) load_lds4(Mb + kbase + tid, &Mk[tid]);
    __syncthreads();  // also orders all waves' qf reads before iter-0 Ps writes

    // S^T tiles: ST[j][i], j = key-tile (rows), i = q-tile (cols).
    f32x4 ST[4][2];
    __builtin_amdgcn_s_setprio(1);
#pragma unroll
    for (int j = 0; j < 4; ++j) {
      float4 mj4 = *reinterpret_cast<const float4*>(&Mk[j * 16 + quad * 4]);
      f32x4 init; init[0] = mj4.x; init[1] = mj4.y; init[2] = mj4.z; init[3] = mj4.w;
#pragma unroll
      for (int i = 0; i < 2; ++i) ST[j][i] = init;
      bf16x8 kf0 = *reinterpret_cast<const bf16x8*>(&Ks[(j * 16 + m16) * 64 + u0]);
      bf16x8 kf1 = *reinterpret_cast<const bf16x8*>(&Ks[(j * 16 + m16) * 64 + u1]);
#pragma unroll
      for (int i = 0; i < 2; ++i) {
        ST[j][i] = __builtin_amdgcn_mfma_f32_16x16x32_bf16(kf0, qf[i][0], ST[j][i], 0, 0, 0);
        ST[j][i] = __builtin_amdgcn_mfma_f32_16x16x32_bf16(kf1, qf[i][1], ST[j][i], 0, 0, 0);
      }
    }
    __builtin_amdgcn_s_setprio(0);

    // Softmax numerator + truncation pack + b64 spill into P (A-layout).
    const int kc_w = (quad >> 1);
    const int inner = (quad & 1) * 4;
#pragma unroll
    for (int j = 0; j < 4; ++j)
#pragma unroll
      for (int i = 0; i < 2; ++i) {
        float p0 = __builtin_amdgcn_exp2f(ST[j][i][0]);
        float p1 = __builtin_amdgcn_exp2f(ST[j][i][1]);
        float p2 = __builtin_amdgcn_exp2f(ST[j][i][2]);
        float p3 = __builtin_amdgcn_exp2f(ST[j][i][3]);
        uint2 pk;
        pk.x = __builtin_amdgcn_perm(__builtin_bit_cast(unsigned, p1),
                                     __builtin_bit_cast(unsigned, p0), 0x07060302u);
        pk.y = __builtin_amdgcn_perm(__builtin_bit_cast(unsigned, p3),
                                     __builtin_bit_cast(unsigned, p2), 0x07060302u);
        *reinterpret_cast<uint2*>(
            &U[wb + (j * 2 + kc_w) * 264 + (i * 16 + m16) * 8 + inner]) = pk;
      }
    asm volatile("s_waitcnt lgkmcnt(0)" ::: "memory");  // own-wave P RAW

    bf16x8 pf[2][2];
#pragma unroll
    for (int i = 0; i < 2; ++i)
#pragma unroll
      for (int s = 0; s < 2; ++s)
        pf[i][s] = *reinterpret_cast<const bf16x8*>(
            &U[wb + (s * 4 + quad) * 264 + (i * 16 + m16) * 8]);

    // l-accumulate via ones-MFMA: lacc rows == oacc rows (C-layout).
    __builtin_amdgcn_s_setprio(1);
#pragma unroll
    for (int i = 0; i < 2; ++i) {
      lacc[i] = __builtin_amdgcn_mfma_f32_16x16x32_bf16(pf[i][0], ones, lacc[i], 0, 0, 0);
      lacc[i] = __builtin_amdgcn_mfma_f32_16x16x32_bf16(pf[i][1], ones, lacc[i], 0, 0, 0);
    }

#pragma unroll
    for (int j = 0; j < 4; ++j) {
      bf16x8 vf0 = *reinterpret_cast<const bf16x8*>(&Vs[(j * 16 + m16) * 64 + u0]);
      bf16x8 vf1 = *reinterpret_cast<const bf16x8*>(&Vs[(j * 16 + m16) * 64 + u1]);
#pragma unroll
      for (int i = 0; i < 2; ++i) {
        oacc[i][j] = __builtin_amdgcn_mfma_f32_16x16x32_bf16(pf[i][0], vf0, oacc[i][j], 0, 0, 0);
        oacc[i][j] = __builtin_amdgcn_mfma_f32_16x16x32_bf16(pf[i][1], vf1, oacc[i][j], 0, 0, 0);
      }
    }
    __builtin_amdgcn_s_setprio(0);
    __syncthreads();
  }

#pragma unroll
  for (int i = 0; i < 2; ++i)
#pragma unroll
    for (int j = 0; j < 4; ++j) {
      int d = j * 16 + m16;
#pragma unroll
      for (int rg = 0; rg < 4; ++rg) {
        int ql = qb * 256 + w * 32 + i * 16 + quad * 4 + rg;
        Out[(b * kL + ql) * kE + h * kHD + d] =
            f2bf(oacc[i][j][rg] / lacc[i][rg]);
      }
    }
}

extern "C" void kernel_launch(void* const* d_in, const int* in_sizes, int n_in,
                              void* d_out, int out_size, void* d_ws, size_t ws_size,
                              hipStream_t stream) {
  const float* x  = (const float*)d_in[0];
  const int* mask = (const int*)d_in[1];
  const float* Wq = (const float*)d_in[2];
  const float* bq = (const float*)d_in[3];
  const float* Wk = (const float*)d_in[4];
  const float* bk = (const float*)d_in[5];
  const float* Wv = (const float*)d_in[6];
  const float* bv = (const float*)d_in[7];
  const float* Wo = (const float*)d_in[8];
  const float* bo = (const float*)d_in[9];

  short* ws  = (short*)d_ws;
  short* xb  = ws;                  // 8388608 shorts
  short* Wqb = xb  + 8388608;       // 4 x 1048576, contiguous
  short* Wkb = Wqb + 1048576;
  short* Wvb = Wkb + 1048576;
  short* Wob = Wvb + 1048576;
  short* Qb  = Wob + 1048576;       // 8388608 each
  short* Kb  = Qb  + 8388608;
  short* Vtb = Kb  + 8388608;
  short* AOb = Vtb + 8388608;       // doubles as Vl before attention runs
  float* Mkf = (float*)(AOb + 8388608);  // 8192 floats

  k_prep<<<12320, 256, 0, stream>>>(x, Wq, Wk, Wv, Wo, mask, xb, Wqb, Mkf);
  // V row-major into AOb (dead until attention runs), then transpose into Vtb.
  k_gemm_qkv<<<dim3(24, 32), 512, 0, stream>>>(xb, Wqb, Wkb, Wvb, bq, bk, bv, Qb, Kb, AOb);
  k_trv<<<dim3(32, 64), 256, 0, stream>>>(AOb, Vtb);
  k_attn<<<dim3(8, 64), 512, 0, stream>>>(Qb, Kb, Vtb, Mkf, AOb);
  k_gemm_out<<<dim3(8, 32), 512, 0, stream>>>(AOb, Wob, bo, (float*)d_out);
}